// Round 5
// baseline (117.782 us; speedup 1.0000x reference)
//
#include <hip/hip_runtime.h>
#include <stdint.h>
#include <math.h>

#define A_N 65536
#define B_N 16
#define T_N 64
#define NB  (A_N / 256)      // k1 blocks per image = 256
#define EPSF 1e-6f

// ---------------------------------------------------------------------------
// Workspace:
//   keys        : B * NB * 64 * u64  = 2 MiB   @ 0        (hi=iou bits, lo=~anchor)
//   code        : B * A * u8         = 1 MiB   @ 2 MiB    (thr flag)
//   partials    : B * NB * 4 * f32   = 64 KiB  @ 3 MiB
//   corrections : B * 4 * f32        = 256 B   @ 3 MiB+64K
//   pack        : B * 64 * 8 * f32   = 32 KiB  @ 3 MiB+128K  ({x1,y1,x2,y2,area,-,-,-})
// ---------------------------------------------------------------------------

// single definition used by EVERY path so iou bits are identical everywhere
__device__ __forceinline__ float iou_at(float4 an, float a1, float tx1, float ty1,
                                        float tx2, float ty2, float tar)
{
    float x1 = fmaxf(an.x, tx1), y1 = fmaxf(an.y, ty1);
    float x2 = fminf(an.z, tx2), y2 = fminf(an.w, ty2);
    float inter = fmaxf(x2 - x1, 0.f) * fmaxf(y2 - y1, 0.f);
    float ue = ((a1 + tar) - inter) + EPSF;          // np-exact association
    return inter / ue;                               // IEEE-exact
}

// K0: pack target boxes + areas, 32B stride (scalar-load friendly).
__global__ __launch_bounds__(1024) void k0_pack(
    const float4* __restrict__ tboxes, float* __restrict__ pack)
{
    const int i = threadIdx.x;              // 0..1023 = B*T
    float4 t = tboxes[i];
    float* p = pack + i * 8;
    p[0] = t.x; p[1] = t.y; p[2] = t.z; p[3] = t.w;
    p[4] = (t.z - t.x) * (t.w - t.y);
    p[5] = 0.f; p[6] = 0.f; p[7] = 0.f;
}

// K1: minimal hot loop (15 VALU, no LDS) -> candidate bitmask; exact two-phase
//     32-bit resolution; fused losses under pos:=thr.
__global__ __launch_bounds__(256) void k1_main(
    const float4* __restrict__ anchors,
    const float4* __restrict__ bbox,
    const float*  __restrict__ conf,
    const float4* __restrict__ cls,       // 20 floats/anchor = 5 x float4
    const float*  __restrict__ pack,
    const int*    __restrict__ tlabels,
    unsigned long long* __restrict__ keys,
    unsigned char* __restrict__ code,
    float* __restrict__ partials)
{
    __shared__ float4 tb[T_N];
    __shared__ float  ta[T_N];
    __shared__ int    tl[T_N];
    __shared__ unsigned int slot_hi[T_N];
    __shared__ unsigned int slot_lo[T_N];
    const int b   = blockIdx.y;
    const int tid = threadIdx.x;
    const float* pk = pack + (size_t)b * T_N * 8;
    if (tid < T_N) {
        const float* q = pk + tid * 8;
        tb[tid] = make_float4(q[0], q[1], q[2], q[3]);
        ta[tid] = q[4];
        tl[tid] = tlabels[b * T_N + tid];
        slot_hi[tid] = 0u;
        slot_lo[tid] = 0u;
    }
    __syncthreads();

    const int a = blockIdx.x * 256 + tid;
    const float4 an = anchors[a];
    const float a1 = (an.z - an.x) * (an.w - an.y);
    const unsigned int lo = ~(unsigned int)a;   // smaller idx -> larger lo

    // hot loop: candidate bit only (superset of iou>=0.25; exact winners later)
    unsigned int mlo = 0u, mhi = 0u;
    #pragma unroll 8
    for (int s = 0; s < 32; ++s) {
        const float* q = pk + s * 8;            // uniform -> s_load
        float x1 = fmaxf(an.x, q[0]), y1 = fmaxf(an.y, q[1]);
        float x2 = fminf(an.z, q[2]), y2 = fminf(an.w, q[3]);
        float inter = fmaxf(x2 - x1, 0.f) * fmaxf(y2 - y1, 0.f);
        float ue = ((a1 + q[4]) - inter) + EPSF;
        mlo = mlo + mlo + ((fmaf(-0.2499f, ue, inter) >= 0.f) ? 1u : 0u); // bit 31-s
    }
    #pragma unroll 8
    for (int s = 32; s < 64; ++s) {
        const float* q = pk + s * 8;
        float x1 = fmaxf(an.x, q[0]), y1 = fmaxf(an.y, q[1]);
        float x2 = fminf(an.z, q[2]), y2 = fminf(an.w, q[3]);
        float inter = fmaxf(x2 - x1, 0.f) * fmaxf(y2 - y1, 0.f);
        float ue = ((a1 + q[4]) - inter) + EPSF;
        mhi = mhi + mhi + ((fmaf(-0.2499f, ue, inter) >= 0.f) ? 1u : 0u); // bit 63-s
    }

    // pass 1: exact iou per candidate (ascending s = first-max), block max bits
    unsigned int bb = 0u; int bt = 0;
    {
        unsigned int w = mlo;
        while (w) {
            int z = __builtin_clz(w); w &= ~(0x80000000u >> z);
            float iou = iou_at(an, a1, tb[z].x, tb[z].y, tb[z].z, tb[z].w, ta[z]);
            unsigned int u = __float_as_uint(iou);
            if (u > bb) { bb = u; bt = z; }
            atomicMax(&slot_hi[z], u);          // native ds_max_u32
        }
        w = mhi;
        while (w) {
            int z = __builtin_clz(w); w &= ~(0x80000000u >> z);
            int s = 32 + z;
            float iou = iou_at(an, a1, tb[s].x, tb[s].y, tb[s].z, tb[s].w, ta[s]);
            unsigned int u = __float_as_uint(iou);
            if (u > bb) { bb = u; bt = s; }
            atomicMax(&slot_hi[s], u);
        }
    }
    __syncthreads();
    // pass 2: among max-achievers, min anchor index (first-max ties)
    {
        unsigned int w = mlo;
        while (w) {
            int z = __builtin_clz(w); w &= ~(0x80000000u >> z);
            float iou = iou_at(an, a1, tb[z].x, tb[z].y, tb[z].z, tb[z].w, ta[z]);
            if (__float_as_uint(iou) == slot_hi[z]) atomicMax(&slot_lo[z], lo);
        }
        w = mhi;
        while (w) {
            int z = __builtin_clz(w); w &= ~(0x80000000u >> z);
            int s = 32 + z;
            float iou = iou_at(an, a1, tb[s].x, tb[s].y, tb[s].z, tb[s].w, ta[s]);
            if (__float_as_uint(iou) == slot_hi[s]) atomicMax(&slot_lo[s], lo);
        }
    }

    const bool thr = (bb >= 0x3F000000u);       // quotient >= 0.5f (bits, iou>=0)
    const size_t ba = (size_t)b * A_N + a;
    code[ba] = thr ? 1 : 0;

    // losses with ct := thr
    const float p  = conf[ba];
    const float w  = thr ? (1.f - p) : p;
    const float fw = w * sqrtf(w);                               // w^1.5
    const float bce = thr ? -logf(p + EPSF) : -logf(1.f - p + EPSF);
    const float cterm = bce * fw * 0.5f;                         // alpha == 0.5

    float bterm = 0.f, clterm = 0.f;
    if (thr) {
        const float4 pb = bbox[ba];
        const float4 mb = tb[bt];
        float x1 = fmaxf(pb.x, mb.x), y1 = fmaxf(pb.y, mb.y);
        float x2 = fminf(pb.z, mb.z), y2 = fminf(pb.w, mb.w);
        float inter = fmaxf(x2 - x1, 0.f) * fmaxf(y2 - y1, 0.f);
        float pa1 = (pb.z - pb.x) * (pb.w - pb.y);
        float pa2 = (mb.z - mb.x) * (mb.w - mb.y);
        float uni = pa1 + pa2 - inter;
        float iou = inter / (uni + EPSF);
        float ex1 = fminf(pb.x, mb.x), ey1 = fminf(pb.y, mb.y);
        float ex2 = fmaxf(pb.z, mb.z), ey2 = fmaxf(pb.w, mb.w);
        float enc = (ex2 - ex1) * (ey2 - ey1);
        float giou = iou - (enc - uni) / (enc + EPSF);
        float gl = 1.f - giou;
        float l1 = 0.25f * (fabsf(pb.x - mb.x) + fabsf(pb.y - mb.y) +
                            fabsf(pb.z - mb.z) + fabsf(pb.w - mb.w));
        bterm = gl + 0.5f * l1;

        const int lab = tl[bt] - 1;                 // 0..19
        const float4* cp = cls + ba * 5;
        float s2 = 0.f, xl = 0.f;
        #pragma unroll
        for (int q = 0; q < 5; ++q) {
            float4 v = cp[q];
            float xs[4] = {v.x, v.y, v.z, v.w};
            #pragma unroll
            for (int j = 0; j < 4; ++j) {
                float x = xs[j];
                s2 += fmaxf(x, 0.f) + log1pf(expf(-fabsf(x)));
                if (q * 4 + j == lab) xl = x;
            }
        }
        clterm = (s2 - xl) * (1.f / 20.f);
    }

    float r0 = cterm, r1 = thr ? 1.f : 0.f, r2 = bterm, r3 = clterm;
    #pragma unroll
    for (int off = 32; off; off >>= 1) {
        r0 += __shfl_down(r0, off, 64);
        r1 += __shfl_down(r1, off, 64);
        r2 += __shfl_down(r2, off, 64);
        r3 += __shfl_down(r3, off, 64);
    }
    __shared__ float red[4][4];
    const int wv = tid >> 6;
    if ((tid & 63) == 0) { red[wv][0] = r0; red[wv][1] = r1; red[wv][2] = r2; red[wv][3] = r3; }
    __syncthreads();   // also fences pass-2 atomics before slot readback
    if (tid < 4) {
        float v = red[0][tid] + red[1][tid] + red[2][tid] + red[3][tid];
        partials[(((size_t)b * NB) + blockIdx.x) * 4 + tid] = v;
    }
    if (tid < T_N)
        keys[(((size_t)b * NB + blockIdx.x) << 6) | tid] =
            ((unsigned long long)slot_hi[tid] << 32) | (unsigned long long)slot_lo[tid];
}

// K2: per image — reduce keys to winners, exact fallback for empty targets,
//     forced-only corrections with exact row-argmax recompute.
__global__ __launch_bounds__(1024) void k2_all(
    const unsigned long long* __restrict__ keys,
    const float4* __restrict__ anchors,
    const float4* __restrict__ bbox,
    const float*  __restrict__ conf,
    const float4* __restrict__ cls,
    const float*  __restrict__ pack,
    const int*    __restrict__ tlabels,
    const unsigned char* __restrict__ code,
    float* __restrict__ corrections)
{
    __shared__ unsigned long long sh[16][64];
    __shared__ unsigned long long sw[16];
    __shared__ unsigned int winner[64];
    __shared__ int emptyList[64];
    __shared__ int nEmpty;
    const int b = blockIdx.x, tid = threadIdx.x;
    const int t = tid & 63, g = tid >> 6;
    const float* pk = pack + (size_t)b * T_N * 8;
    if (tid == 0) nEmpty = 0;

    unsigned long long K = 0ull;
    #pragma unroll 4
    for (int i = 0; i < 16; ++i) {
        unsigned long long k = keys[(((size_t)b * NB + (g * 16 + i)) << 6) | t];
        if (k > K) K = k;
    }
    sh[g][t] = K;
    __syncthreads();
    if (tid < 64) {
        unsigned long long m = sh[0][tid];
        #pragma unroll
        for (int g2 = 1; g2 < 16; ++g2) if (sh[g2][tid] > m) m = sh[g2][tid];
        unsigned int lo32 = (unsigned int)(m & 0xFFFFFFFFull);
        if (lo32 != 0u) winner[tid] = ~lo32;
        else { int i = atomicAdd(&nEmpty, 1); emptyList[i] = tid; }
    }
    __syncthreads();

    const int ne = nEmpty;            // normally 0
    for (int e = 0; e < ne; ++e) {
        const int tt = emptyList[e];
        const float* q = pk + tt * 8;
        const float tx1 = q[0], ty1 = q[1], tx2 = q[2], ty2 = q[3], tar = q[4];
        unsigned long long bk = 0ull;
        for (int i = tid; i < A_N; i += 1024) {
            float4 an = anchors[i];
            float a1 = (an.z - an.x) * (an.w - an.y);
            float iou = iou_at(an, a1, tx1, ty1, tx2, ty2, tar);
            unsigned long long key = ((unsigned long long)__float_as_uint(iou) << 32)
                                   | (unsigned long long)(~(unsigned int)i);
            if (key > bk) bk = key;
        }
        #pragma unroll
        for (int off = 32; off; off >>= 1) {
            unsigned long long o = __shfl_down(bk, off, 64);
            if (o > bk) bk = o;
        }
        if ((tid & 63) == 0) sw[g] = bk;
        __syncthreads();
        if (tid == 0) {
            unsigned long long m = sw[0];
            #pragma unroll
            for (int i = 1; i < 16; ++i) if (sw[i] > m) m = sw[i];
            winner[tt] = ~(unsigned int)(m & 0xFFFFFFFFull);
        }
        __syncthreads();
    }

    // corrections: first wave, dedupe winners (lowest target owns), exact
    // row-argmax recompute for matched target.
    if (tid < 64) {
        const unsigned int wa = winner[tid];
        bool owner = true;
        for (int k = 0; k < 64; ++k) {
            unsigned int o = __shfl(wa, k, 64);
            if (k < tid && o == wa) owner = false;
        }
        const size_t ba = (size_t)b * A_N + wa;
        float d0 = 0.f, d1 = 0.f, d2 = 0.f, d3 = 0.f;
        if (owner && code[ba] == 0) {
            // exact best_target_idx for this anchor (full row, first-max)
            const float4 aw = anchors[wa];
            const float aw1 = (aw.z - aw.x) * (aw.w - aw.y);
            unsigned int bb = 0u; int bt = 0;
            for (int s = 0; s < T_N; ++s) {
                const float* q = pk + s * 8;
                float iou = iou_at(aw, aw1, q[0], q[1], q[2], q[3], q[4]);
                unsigned int u = __float_as_uint(iou);
                if (u > bb) { bb = u; bt = s; }
            }
            const float p = conf[ba];
            float w1 = 1.f - p;
            float f1 = -logf(p + EPSF)       * (w1 * sqrtf(w1)) * 0.5f;
            float f0 = -logf(1.f - p + EPSF) * (p  * sqrtf(p))  * 0.5f;
            d0 = f1 - f0;
            d1 = 1.f;
            const float* qb = pk + bt * 8;
            const float4 pb = bbox[ba];
            const float4 mb = make_float4(qb[0], qb[1], qb[2], qb[3]);
            float x1 = fmaxf(pb.x, mb.x), y1 = fmaxf(pb.y, mb.y);
            float x2 = fminf(pb.z, mb.z), y2 = fminf(pb.w, mb.w);
            float inter = fmaxf(x2 - x1, 0.f) * fmaxf(y2 - y1, 0.f);
            float pa1 = (pb.z - pb.x) * (pb.w - pb.y);
            float pa2 = (mb.z - mb.x) * (mb.w - mb.y);
            float uni = pa1 + pa2 - inter;
            float iou = inter / (uni + EPSF);
            float ex1 = fminf(pb.x, mb.x), ey1 = fminf(pb.y, mb.y);
            float ex2 = fmaxf(pb.z, mb.z), ey2 = fmaxf(pb.w, mb.w);
            float enc = (ex2 - ex1) * (ey2 - ey1);
            float giou = iou - (enc - uni) / (enc + EPSF);
            float gl = 1.f - giou;
            float l1 = 0.25f * (fabsf(pb.x - mb.x) + fabsf(pb.y - mb.y) +
                                fabsf(pb.z - mb.z) + fabsf(pb.w - mb.w));
            d2 = gl + 0.5f * l1;

            const int lab = tlabels[b * T_N + bt] - 1;
            const float4* cp = cls + ba * 5;
            float s2 = 0.f, xl = 0.f;
            #pragma unroll
            for (int q2 = 0; q2 < 5; ++q2) {
                float4 v = cp[q2];
                float xs[4] = {v.x, v.y, v.z, v.w};
                #pragma unroll
                for (int j = 0; j < 4; ++j) {
                    float x = xs[j];
                    s2 += fmaxf(x, 0.f) + log1pf(expf(-fabsf(x)));
                    if (q2 * 4 + j == lab) xl = x;
                }
            }
            d3 = (s2 - xl) * (1.f / 20.f);
        }
        #pragma unroll
        for (int off = 32; off; off >>= 1) {
            d0 += __shfl_down(d0, off, 64);
            d1 += __shfl_down(d1, off, 64);
            d2 += __shfl_down(d2, off, 64);
            d3 += __shfl_down(d3, off, 64);
        }
        if (tid == 0) {
            corrections[b * 4 + 0] = d0;
            corrections[b * 4 + 1] = d1;
            corrections[b * 4 + 2] = d2;
            corrections[b * 4 + 3] = d3;
        }
    }
}

// K4: final per-image losses and batch means -> 4 outputs.
__global__ __launch_bounds__(1024) void k4_final(
    const float* __restrict__ partials,
    const float* __restrict__ corrections,
    float* __restrict__ out)
{
    const int tid  = threadIdx.x;
    const int b    = tid >> 6;
    const int lane = tid & 63;
    float s0 = 0.f, s1 = 0.f, s2 = 0.f, s3 = 0.f;
    #pragma unroll
    for (int i = 0; i < 4; ++i) {
        const float* p = partials + (((size_t)b * NB) + (lane + 64 * i)) * 4;
        s0 += p[0]; s1 += p[1]; s2 += p[2]; s3 += p[3];
    }
    #pragma unroll
    for (int off = 32; off; off >>= 1) {
        s0 += __shfl_down(s0, off, 64);
        s1 += __shfl_down(s1, off, 64);
        s2 += __shfl_down(s2, off, 64);
        s3 += __shfl_down(s3, off, 64);
    }
    __shared__ float L[16][3];
    if (lane == 0) {
        s0 += corrections[b * 4 + 0];
        s1 += corrections[b * 4 + 1];
        s2 += corrections[b * 4 + 2];
        s3 += corrections[b * 4 + 3];
        float confL = s0 / (float)A_N;
        float npos  = fmaxf(s1, 1.f);
        L[b][0] = confL;
        L[b][1] = s2 / npos;
        L[b][2] = s3 / npos;
    }
    __syncthreads();
    if (tid == 0) {
        float cm = 0.f, bm = 0.f, lm = 0.f;
        #pragma unroll
        for (int i = 0; i < 16; ++i) { cm += L[i][0]; bm += L[i][1]; lm += L[i][2]; }
        cm *= (1.f / 16.f); bm *= (1.f / 16.f); lm *= (1.f / 16.f);
        out[0] = cm + bm + lm;
        out[1] = cm;
        out[2] = bm;
        out[3] = lm;
    }
}

extern "C" void kernel_launch(void* const* d_in, const int* in_sizes, int n_in,
                              void* d_out, int out_size, void* d_ws, size_t ws_size,
                              hipStream_t stream)
{
    const float4* bbox    = (const float4*)d_in[0];
    const float*  conf    = (const float*) d_in[1];
    const float4* cls     = (const float4*)d_in[2];
    const float4* anchors = (const float4*)d_in[3];
    const float4* tboxes  = (const float4*)d_in[4];
    const int*    tlabels = (const int*)   d_in[5];
    float* out = (float*)d_out;

    char* ws = (char*)d_ws;
    unsigned long long* keys        = (unsigned long long*)ws;                    // 2 MiB
    unsigned char*      code        = (unsigned char*)(ws + (2u << 20));          // 1 MiB
    float*              partials    = (float*)(ws + (3u << 20));                  // 64 KiB
    float*              corrections = (float*)(ws + (3u << 20) + (64u << 10));    // 256 B
    float*              pack        = (float*)(ws + (3u << 20) + (128u << 10));   // 32 KiB

    k0_pack <<<1, 1024, 0, stream>>>(tboxes, pack);
    k1_main <<<dim3(NB, B_N), 256, 0, stream>>>(anchors, bbox, conf, cls, pack,
                                                tlabels, keys, code, partials);
    k2_all  <<<B_N, 1024, 0, stream>>>(keys, anchors, bbox, conf, cls, pack,
                                       tlabels, code, corrections);
    k4_final<<<1, 1024, 0, stream>>>(partials, corrections, out);
}

// Round 7
// 77.042 us; speedup vs baseline: 1.5288x; 1.5288x over previous
//
#include <hip/hip_runtime.h>
#include <stdint.h>
#include <math.h>

#define A_N 65536
#define B_N 16
#define T_N 64
#define NB  (A_N / 256)      // k1 blocks per image = 256
#define NB3 32               // k3 blocks per image
#define EPSF 1e-6f
#define LN2F   0.69314718055994531f
#define LOG2EF 1.4426950408889634f

// fast hw transcendentals: v_exp_f32 (2^x), v_log_f32 (log2 x)
#define EXP2F(x) __builtin_amdgcn_exp2f(x)
#define LOG2F(x) __builtin_amdgcn_logf(x)

// ---------------------------------------------------------------------------
// Workspace:
//   keys     : B * NB * 64 * u64 = 2 MiB   @ 0          (hi=iou bits, lo=~anchor)
//   code     : B * A * u8        = 1 MiB   @ 2 MiB      (bt | thr<<7)
//   partials : B * NB * 2 * f32  = 32 KiB  @ 3 MiB      (conf term, ct) per k1 block
//   bparts   : B * NB3 * 2 * f32 = 4 KiB   @ 3 MiB+32K  (bbox, cls) per k3 block
//   corr     : B * 4 * f32       = 256 B   @ 3 MiB+36K
//   posTotal : B * u32           = 64 B    @ 3 MiB+40K
//   pack     : B * 64 * 8 * f32  = 32 KiB  @ 3 MiB+64K  ({x1,y1,x2,y2,area,..})
//   posIdx   : B * A * u32       = 4 MiB   @ 4 MiB
// ---------------------------------------------------------------------------

// single definition used by EVERY path so iou bits are identical everywhere
__device__ __forceinline__ float iou_at(float4 an, float a1, float tx1, float ty1,
                                        float tx2, float ty2, float tar)
{
    float x1 = fmaxf(an.x, tx1), y1 = fmaxf(an.y, ty1);
    float x2 = fminf(an.z, tx2), y2 = fminf(an.w, ty2);
    float inter = fmaxf(x2 - x1, 0.f) * fmaxf(y2 - y1, 0.f);
    float ue = ((a1 + tar) - inter) + EPSF;          // np-exact association
    return inter / ue;                               // IEEE-exact
}

// focal BCE conf term; shared by k1 and corrections so f0 cancels bitwise
__device__ __forceinline__ float conf_term(float p, bool pos)
{
    float u = pos ? p : (1.f - p);       // prob of the "correct" side
    float w = 1.f - u;                   // focal weight base
    float bce = -LN2F * LOG2F(u + EPSF);
    float fw = w * sqrtf(w);             // w^1.5
    return bce * fw * 0.5f;              // alpha factor == 0.5
}

// log1p(exp(-|x|)) via raw v_exp/v_log (1-ulp class; tolerance is 5.9e-2)
__device__ __forceinline__ float softplus_negabs(float x)
{
    float y = EXP2F(fabsf(x) * -LOG2EF);
    return LN2F * LOG2F(1.0f + y);
}

// stable-BCE-with-logits sum over 20 classes, one-hot via direct gather
__device__ __forceinline__ float cls_term(const float4* cp, const float* cls_f,
                                          size_t ba, int lab)
{
    float s2 = 0.f;
    #pragma unroll
    for (int q = 0; q < 5; ++q) {
        float4 v = cp[q];
        s2 += fmaxf(v.x, 0.f) + softplus_negabs(v.x);
        s2 += fmaxf(v.y, 0.f) + softplus_negabs(v.y);
        s2 += fmaxf(v.z, 0.f) + softplus_negabs(v.z);
        s2 += fmaxf(v.w, 0.f) + softplus_negabs(v.w);
    }
    float xl = cls_f[ba * 20 + (size_t)lab];
    return (s2 - xl) * (1.f / 20.f);
}

// giou + 0.5*l1 term for a matched pair
__device__ __forceinline__ float bterm_at(float4 pb, float4 mb)
{
    float x1 = fmaxf(pb.x, mb.x), y1 = fmaxf(pb.y, mb.y);
    float x2 = fminf(pb.z, mb.z), y2 = fminf(pb.w, mb.w);
    float inter = fmaxf(x2 - x1, 0.f) * fmaxf(y2 - y1, 0.f);
    float pa1 = (pb.z - pb.x) * (pb.w - pb.y);
    float pa2 = (mb.z - mb.x) * (mb.w - mb.y);
    float uni = pa1 + pa2 - inter;
    float iou = inter / (uni + EPSF);
    float ex1 = fminf(pb.x, mb.x), ey1 = fminf(pb.y, mb.y);
    float ex2 = fmaxf(pb.z, mb.z), ey2 = fmaxf(pb.w, mb.w);
    float enc = (ex2 - ex1) * (ey2 - ey1);
    float giou = iou - (enc - uni) / (enc + EPSF);
    float l1 = 0.25f * (fabsf(pb.x - mb.x) + fabsf(pb.y - mb.y) +
                        fabsf(pb.z - mb.z) + fabsf(pb.w - mb.w));
    return (1.f - giou) + 0.5f * l1;
}

// K0: pack target boxes + areas, 32B stride (scalar-load friendly).
__global__ __launch_bounds__(1024) void k0_pack(
    const float4* __restrict__ tboxes, float* __restrict__ pack)
{
    const int i = threadIdx.x;              // 0..1023 = B*T
    float4 t = tboxes[i];
    float* p = pack + i * 8;
    p[0] = t.x; p[1] = t.y; p[2] = t.z; p[3] = t.w;
    p[4] = (t.z - t.x) * (t.w - t.y);
    p[5] = 0.f; p[6] = 0.f; p[7] = 0.f;
}

// K1: minimal hot loop -> candidate bitmask; exact two-phase 32-bit
//     resolution; conf loss only (pos losses deferred to k3).
__global__ __launch_bounds__(256) void k1_main(
    const float4* __restrict__ anchors,
    const float*  __restrict__ conf,
    const float*  __restrict__ pack,
    unsigned long long* __restrict__ keys,
    unsigned char* __restrict__ code,
    float* __restrict__ partials)
{
    __shared__ float4 tb[T_N];
    __shared__ float  ta[T_N];
    __shared__ unsigned int slot_hi[T_N];
    __shared__ unsigned int slot_lo[T_N];
    const int b   = blockIdx.y;
    const int tid = threadIdx.x;
    const float* pk = pack + (size_t)b * T_N * 8;
    if (tid < T_N) {
        const float* q = pk + tid * 8;
        tb[tid] = make_float4(q[0], q[1], q[2], q[3]);
        ta[tid] = q[4];
        slot_hi[tid] = 0u;
        slot_lo[tid] = 0u;
    }
    __syncthreads();

    const int a = blockIdx.x * 256 + tid;
    const float4 an = anchors[a];
    const float a1 = (an.z - an.x) * (an.w - an.y);
    const unsigned int lo = ~(unsigned int)a;   // smaller idx -> larger lo

    // hot loop: candidate bit only (superset of iou>=0.25; exact winners later)
    unsigned int mlo = 0u, mhi = 0u;
    #pragma unroll 8
    for (int s = 0; s < 32; ++s) {
        const float* q = pk + s * 8;            // uniform -> s_load
        float x1 = fmaxf(an.x, q[0]), y1 = fmaxf(an.y, q[1]);
        float x2 = fminf(an.z, q[2]), y2 = fminf(an.w, q[3]);
        float inter = fmaxf(x2 - x1, 0.f) * fmaxf(y2 - y1, 0.f);
        float ue = ((a1 + q[4]) - inter) + EPSF;
        mlo = mlo + mlo + ((fmaf(-0.2499f, ue, inter) >= 0.f) ? 1u : 0u); // bit 31-s
    }
    #pragma unroll 8
    for (int s = 32; s < 64; ++s) {
        const float* q = pk + s * 8;
        float x1 = fmaxf(an.x, q[0]), y1 = fmaxf(an.y, q[1]);
        float x2 = fminf(an.z, q[2]), y2 = fminf(an.w, q[3]);
        float inter = fmaxf(x2 - x1, 0.f) * fmaxf(y2 - y1, 0.f);
        float ue = ((a1 + q[4]) - inter) + EPSF;
        mhi = mhi + mhi + ((fmaf(-0.2499f, ue, inter) >= 0.f) ? 1u : 0u); // bit 63-s
    }

    // pass 1: exact iou per candidate (ascending s = first-max), block max bits
    unsigned int bb = 0u; int bt = 0;
    {
        unsigned int w = mlo;
        while (w) {
            int z = __builtin_clz(w); w &= ~(0x80000000u >> z);
            float iou = iou_at(an, a1, tb[z].x, tb[z].y, tb[z].z, tb[z].w, ta[z]);
            unsigned int u = __float_as_uint(iou);
            if (u > bb) { bb = u; bt = z; }
            atomicMax(&slot_hi[z], u);          // native ds_max_u32
        }
        w = mhi;
        while (w) {
            int z = __builtin_clz(w); w &= ~(0x80000000u >> z);
            int s = 32 + z;
            float iou = iou_at(an, a1, tb[s].x, tb[s].y, tb[s].z, tb[s].w, ta[s]);
            unsigned int u = __float_as_uint(iou);
            if (u > bb) { bb = u; bt = s; }
            atomicMax(&slot_hi[s], u);
        }
    }
    __syncthreads();
    // pass 2: among max-achievers, min anchor index (first-max ties)
    {
        unsigned int w = mlo;
        while (w) {
            int z = __builtin_clz(w); w &= ~(0x80000000u >> z);
            float iou = iou_at(an, a1, tb[z].x, tb[z].y, tb[z].z, tb[z].w, ta[z]);
            if (__float_as_uint(iou) == slot_hi[z]) atomicMax(&slot_lo[z], lo);
        }
        w = mhi;
        while (w) {
            int z = __builtin_clz(w); w &= ~(0x80000000u >> z);
            int s = 32 + z;
            float iou = iou_at(an, a1, tb[s].x, tb[s].y, tb[s].z, tb[s].w, ta[s]);
            if (__float_as_uint(iou) == slot_hi[s]) atomicMax(&slot_lo[s], lo);
        }
    }

    const bool thr = (bb >= 0x3F000000u);       // max quotient >= 0.5f
    const size_t ba = (size_t)b * A_N + a;
    code[ba] = (unsigned char)(bt | (thr ? 128 : 0));

    const float cterm = conf_term(conf[ba], thr);

    float r0 = cterm, r1 = thr ? 1.f : 0.f;
    #pragma unroll
    for (int off = 32; off; off >>= 1) {
        r0 += __shfl_down(r0, off, 64);
        r1 += __shfl_down(r1, off, 64);
    }
    __shared__ float red[4][2];
    const int wv = tid >> 6;
    if ((tid & 63) == 0) { red[wv][0] = r0; red[wv][1] = r1; }
    __syncthreads();   // also fences pass-2 atomics before slot readback
    if (tid < 2) {
        float v = red[0][tid] + red[1][tid] + red[2][tid] + red[3][tid];
        partials[(((size_t)b * NB) + blockIdx.x) * 2 + tid] = v;
    }
    if (tid < T_N)
        keys[(((size_t)b * NB + blockIdx.x) << 6) | tid] =
            ((unsigned long long)slot_hi[tid] << 32) | (unsigned long long)slot_lo[tid];
}

__device__ __forceinline__ unsigned int cnt4(uint4 v)
{
    return __popc(v.x & 0x80808080u) + __popc(v.y & 0x80808080u) +
           __popc(v.z & 0x80808080u) + __popc(v.w & 0x80808080u);
}

// K2: per image — winners + fallback + forced-only corrections + stable
//     compaction of positive anchors. One block per image.
__global__ __launch_bounds__(1024) void k2_all(
    const unsigned long long* __restrict__ keys,
    const float4* __restrict__ anchors,
    const float4* __restrict__ bbox,
    const float*  __restrict__ conf,
    const float4* __restrict__ cls,
    const float*  __restrict__ pack,
    const int*    __restrict__ tlabels,
    const unsigned char* __restrict__ code,
    float* __restrict__ corrections,
    unsigned int* __restrict__ posIdx,
    unsigned int* __restrict__ posTotal)
{
    __shared__ unsigned long long sh[16][64];
    __shared__ unsigned long long sw[16];
    __shared__ unsigned int winner[64];
    __shared__ int emptyList[64];
    __shared__ int nEmpty;
    __shared__ unsigned int sc[1024];
    const int b = blockIdx.x, tid = threadIdx.x;
    const int t = tid & 63, g = tid >> 6;
    const float* pk = pack + (size_t)b * T_N * 8;
    const float* cls_f = (const float*)cls;
    if (tid == 0) nEmpty = 0;

    unsigned long long K = 0ull;
    #pragma unroll 4
    for (int i = 0; i < 16; ++i) {
        unsigned long long k = keys[(((size_t)b * NB + (g * 16 + i)) << 6) | t];
        if (k > K) K = k;
    }
    sh[g][t] = K;
    __syncthreads();
    if (tid < 64) {
        unsigned long long m = sh[0][tid];
        #pragma unroll
        for (int g2 = 1; g2 < 16; ++g2) if (sh[g2][tid] > m) m = sh[g2][tid];
        unsigned int lo32 = (unsigned int)(m & 0xFFFFFFFFull);
        if (lo32 != 0u) winner[tid] = ~lo32;
        else { int i = atomicAdd(&nEmpty, 1); emptyList[i] = tid; }
    }
    __syncthreads();

    const int ne = nEmpty;            // normally 0
    for (int e = 0; e < ne; ++e) {
        const int tt = emptyList[e];
        const float* q = pk + tt * 8;
        const float tx1 = q[0], ty1 = q[1], tx2 = q[2], ty2 = q[3], tar = q[4];
        unsigned long long bk = 0ull;
        for (int i = tid; i < A_N; i += 1024) {
            float4 an = anchors[i];
            float a1 = (an.z - an.x) * (an.w - an.y);
            float iou = iou_at(an, a1, tx1, ty1, tx2, ty2, tar);
            unsigned long long key = ((unsigned long long)__float_as_uint(iou) << 32)
                                   | (unsigned long long)(~(unsigned int)i);
            if (key > bk) bk = key;
        }
        #pragma unroll
        for (int off = 32; off; off >>= 1) {
            unsigned long long o = __shfl_down(bk, off, 64);
            if (o > bk) bk = o;
        }
        if ((tid & 63) == 0) sw[g] = bk;
        __syncthreads();
        if (tid == 0) {
            unsigned long long m = sw[0];
            #pragma unroll
            for (int i = 1; i < 16; ++i) if (sw[i] > m) m = sw[i];
            winner[tt] = ~(unsigned int)(m & 0xFFFFFFFFull);
        }
        __syncthreads();
    }

    // corrections: first wave, dedupe winners (lowest target owns), exact
    // row-argmax recompute for matched target.
    if (tid < 64) {
        const unsigned int wa = winner[tid];
        bool owner = true;
        for (int k = 0; k < 64; ++k) {
            unsigned int o = __shfl(wa, k, 64);
            if (k < tid && o == wa) owner = false;
        }
        const size_t ba = (size_t)b * A_N + wa;
        float d0 = 0.f, d1 = 0.f, d2 = 0.f, d3 = 0.f;
        if (owner && (code[ba] & 128) == 0) {
            // exact best_target_idx for this anchor (full row, first-max)
            const float4 aw = anchors[wa];
            const float aw1 = (aw.z - aw.x) * (aw.w - aw.y);
            unsigned int bb = 0u; int bt = 0;
            for (int s = 0; s < T_N; ++s) {
                const float* q = pk + s * 8;
                float iou = iou_at(aw, aw1, q[0], q[1], q[2], q[3], q[4]);
                unsigned int u = __float_as_uint(iou);
                if (u > bb) { bb = u; bt = s; }
            }
            const float p = conf[ba];
            d0 = conf_term(p, true) - conf_term(p, false);   // f0 cancels k1's term
            d1 = 1.f;
            const float* qb = pk + bt * 8;
            const float4 pb = bbox[ba];
            const float4 mb = make_float4(qb[0], qb[1], qb[2], qb[3]);
            d2 = bterm_at(pb, mb);
            d3 = cls_term(cls + ba * 5, cls_f, ba, tlabels[b * T_N + bt] - 1);
        }
        #pragma unroll
        for (int off = 32; off; off >>= 1) {
            d0 += __shfl_down(d0, off, 64);
            d1 += __shfl_down(d1, off, 64);
            d2 += __shfl_down(d2, off, 64);
            d3 += __shfl_down(d3, off, 64);
        }
        if (tid == 0) {
            corrections[b * 4 + 0] = d0;
            corrections[b * 4 + 1] = d1;
            corrections[b * 4 + 2] = d2;
            corrections[b * 4 + 3] = d3;
        }
    }
    __syncthreads();

    // stable compaction: thread t owns anchors [t*64, t*64+64)
    {
        const uint4* c4 = (const uint4*)(code + (size_t)b * A_N);
        uint4 v0 = c4[tid * 4 + 0], v1 = c4[tid * 4 + 1];
        uint4 v2 = c4[tid * 4 + 2], v3 = c4[tid * 4 + 3];
        unsigned int cnt = cnt4(v0) + cnt4(v1) + cnt4(v2) + cnt4(v3);
        sc[tid] = cnt;
        __syncthreads();
        for (int off = 1; off < 1024; off <<= 1) {          // Hillis-Steele
            unsigned int v = (tid >= off) ? sc[tid - off] : 0u;
            __syncthreads();
            sc[tid] += v;
            __syncthreads();
        }
        unsigned int idx = sc[tid] - cnt;
        if (tid == 1023) posTotal[b] = sc[1023];
        unsigned int base = (unsigned int)tid * 64u;
        unsigned int* dst = posIdx + (size_t)b * A_N;
        unsigned int dws[16] = {v0.x,v0.y,v0.z,v0.w, v1.x,v1.y,v1.z,v1.w,
                                v2.x,v2.y,v2.z,v2.w, v3.x,v3.y,v3.z,v3.w};
        #pragma unroll
        for (int d = 0; d < 16; ++d) {
            unsigned int dw = dws[d];
            #pragma unroll
            for (int j = 0; j < 4; ++j)
                if ((dw >> (8 * j + 7)) & 1u) dst[idx++] = base + 4u * d + j;
        }
    }
}

// K3: positive-anchor bbox+cls losses over the compacted list.
__global__ __launch_bounds__(256) void k3_pos(
    const float4* __restrict__ bbox,
    const float4* __restrict__ cls,
    const float*  __restrict__ pack,
    const int*    __restrict__ tlabels,
    const unsigned char* __restrict__ code,
    const unsigned int* __restrict__ posIdx,
    const unsigned int* __restrict__ posTotal,
    float* __restrict__ bparts)
{
    __shared__ float4 tb[T_N];
    __shared__ int    tl[T_N];
    const int b = blockIdx.y, blk = blockIdx.x, tid = threadIdx.x;
    const float* pk = pack + (size_t)b * T_N * 8;
    if (tid < T_N) {
        const float* q = pk + tid * 8;
        tb[tid] = make_float4(q[0], q[1], q[2], q[3]);
        tl[tid] = tlabels[b * T_N + tid];
    }
    __syncthreads();
    const float* cls_f = (const float*)cls;
    const unsigned int tot = posTotal[b];
    float sb = 0.f, sl = 0.f;
    for (unsigned int slot = (unsigned int)blk * 256u + tid; slot < tot;
         slot += (unsigned int)NB3 * 256u) {
        const unsigned int a = posIdx[(size_t)b * A_N + slot];
        const size_t ba = (size_t)b * A_N + a;
        const int bt = code[ba] & 63;
        sb += bterm_at(bbox[ba], tb[bt]);
        sl += cls_term(cls + ba * 5, cls_f, ba, tl[bt] - 1);
    }
    #pragma unroll
    for (int off = 32; off; off >>= 1) {
        sb += __shfl_down(sb, off, 64);
        sl += __shfl_down(sl, off, 64);
    }
    __shared__ float red[4][2];
    if ((tid & 63) == 0) { red[tid >> 6][0] = sb; red[tid >> 6][1] = sl; }
    __syncthreads();
    if (tid == 0) {
        float v0 = red[0][0] + red[1][0] + red[2][0] + red[3][0];
        float v1 = red[0][1] + red[1][1] + red[2][1] + red[3][1];
        bparts[((size_t)b * NB3 + blk) * 2 + 0] = v0;
        bparts[((size_t)b * NB3 + blk) * 2 + 1] = v1;
    }
}

// K4: final per-image losses and batch means -> 4 outputs.
__global__ __launch_bounds__(1024) void k4_final(
    const float* __restrict__ partials,
    const float* __restrict__ bparts,
    const float* __restrict__ corrections,
    float* __restrict__ out)
{
    const int tid  = threadIdx.x;
    const int b    = tid >> 6;
    const int lane = tid & 63;
    float s0 = 0.f, s1 = 0.f, s2 = 0.f, s3 = 0.f;
    #pragma unroll
    for (int i = 0; i < 4; ++i) {
        const float* p = partials + (((size_t)b * NB) + (lane + 64 * i)) * 2;
        s0 += p[0]; s1 += p[1];
    }
    if (lane < NB3) {
        const float* q = bparts + (((size_t)b * NB3) + lane) * 2;
        s2 = q[0]; s3 = q[1];
    }
    #pragma unroll
    for (int off = 32; off; off >>= 1) {
        s0 += __shfl_down(s0, off, 64);
        s1 += __shfl_down(s1, off, 64);
        s2 += __shfl_down(s2, off, 64);
        s3 += __shfl_down(s3, off, 64);
    }
    __shared__ float L[16][3];
    if (lane == 0) {
        s0 += corrections[b * 4 + 0];
        s1 += corrections[b * 4 + 1];
        s2 += corrections[b * 4 + 2];
        s3 += corrections[b * 4 + 3];
        float confL = s0 / (float)A_N;
        float npos  = fmaxf(s1, 1.f);
        L[b][0] = confL;
        L[b][1] = s2 / npos;
        L[b][2] = s3 / npos;
    }
    __syncthreads();
    if (tid == 0) {
        float cm = 0.f, bm = 0.f, lm = 0.f;
        #pragma unroll
        for (int i = 0; i < 16; ++i) { cm += L[i][0]; bm += L[i][1]; lm += L[i][2]; }
        cm *= (1.f / 16.f); bm *= (1.f / 16.f); lm *= (1.f / 16.f);
        out[0] = cm + bm + lm;
        out[1] = cm;
        out[2] = bm;
        out[3] = lm;
    }
}

extern "C" void kernel_launch(void* const* d_in, const int* in_sizes, int n_in,
                              void* d_out, int out_size, void* d_ws, size_t ws_size,
                              hipStream_t stream)
{
    const float4* bbox    = (const float4*)d_in[0];
    const float*  conf    = (const float*) d_in[1];
    const float4* cls     = (const float4*)d_in[2];
    const float4* anchors = (const float4*)d_in[3];
    const float4* tboxes  = (const float4*)d_in[4];
    const int*    tlabels = (const int*)   d_in[5];
    float* out = (float*)d_out;

    char* ws = (char*)d_ws;
    unsigned long long* keys     = (unsigned long long*)ws;                    // 2 MiB
    unsigned char*      code     = (unsigned char*)(ws + (2u << 20));          // 1 MiB
    float*        partials       = (float*)(ws + (3u << 20));                  // 32 KiB
    float*        bparts         = (float*)(ws + (3u << 20) + (32u << 10));    // 4 KiB
    float*        corrections    = (float*)(ws + (3u << 20) + (36u << 10));    // 256 B
    unsigned int* posTotal       = (unsigned int*)(ws + (3u << 20) + (40u << 10)); // 64 B
    float*        pack           = (float*)(ws + (3u << 20) + (64u << 10));    // 32 KiB
    unsigned int* posIdx         = (unsigned int*)(ws + (4u << 20));           // 4 MiB

    k0_pack <<<1, 1024, 0, stream>>>(tboxes, pack);
    k1_main <<<dim3(NB, B_N), 256, 0, stream>>>(anchors, conf, pack,
                                                keys, code, partials);
    k2_all  <<<B_N, 1024, 0, stream>>>(keys, anchors, bbox, conf, cls, pack,
                                       tlabels, code, corrections, posIdx, posTotal);
    k3_pos  <<<dim3(NB3, B_N), 256, 0, stream>>>(bbox, cls, pack, tlabels, code,
                                                 posIdx, posTotal, bparts);
    k4_final<<<1, 1024, 0, stream>>>(partials, bparts, corrections, out);
}

// Round 8
// 68.654 us; speedup vs baseline: 1.7156x; 1.1222x over previous
//
#include <hip/hip_runtime.h>
#include <stdint.h>
#include <math.h>

#define A_N 65536
#define B_N 16
#define T_N 64
#define NB  (A_N / 256)      // k1 blocks per image = 256
#define EPSF 1e-6f
#define LN2F   0.69314718055994531f
#define LOG2EF 1.4426950408889634f

// fast hw ops: v_exp_f32 (2^x), v_log_f32 (log2 x), v_rcp_f32, v_sqrt_f32
#define EXP2F(x) __builtin_amdgcn_exp2f(x)
#define LOG2F(x) __builtin_amdgcn_logf(x)
#define RCPF(x)  __builtin_amdgcn_rcpf(x)
#define SQRTF(x) __builtin_amdgcn_sqrtf(x)

// ---------------------------------------------------------------------------
// Workspace:
//   keys     : B * NB * 64 * u64  = 2 MiB   @ 0         (hi=iou bits, lo=~anchor)
//   code     : B * A * u8         = 1 MiB   @ 2 MiB     (bt | thr<<7)
//   partials : B * NB * float4    = 64 KiB  @ 3 MiB     (conf, ct, bbox, cls)
//   lossImg  : B * 3 * f32        = 192 B   @ 3 MiB+64K
//   pack     : B * 64 * 8 * f32   = 32 KiB  @ 3 MiB+128K ({x1,y1,x2,y2,area,st,..})
// ---------------------------------------------------------------------------

// EXACT iou — used by every selection path so bits match everywhere
__device__ __forceinline__ float iou_at(float4 an, float a1, float tx1, float ty1,
                                        float tx2, float ty2, float tar)
{
    float x1 = fmaxf(an.x, tx1), y1 = fmaxf(an.y, ty1);
    float x2 = fminf(an.z, tx2), y2 = fminf(an.w, ty2);
    float inter = fmaxf(x2 - x1, 0.f) * fmaxf(y2 - y1, 0.f);
    float ue = ((a1 + tar) - inter) + EPSF;          // np-exact association
    return inter / ue;                               // IEEE-exact
}

// focal BCE conf term; shared by k1 and corrections so f0 cancels bitwise
__device__ __forceinline__ float conf_term(float p, bool pos)
{
    float u = pos ? p : (1.f - p);       // prob of the "correct" side
    float w = 1.f - u;                   // focal weight base
    float bce = -LN2F * LOG2F(u + EPSF);
    float fw = w * SQRTF(w);             // w^1.5
    return bce * fw * 0.5f;              // alpha factor == 0.5
}

// log1p(exp(-|x|)) via raw v_exp/v_log (1-ulp class; tolerance is 5.9e-2)
__device__ __forceinline__ float softplus_negabs(float x)
{
    float y = EXP2F(fabsf(x) * -LOG2EF);
    return LN2F * LOG2F(1.0f + y);
}

// stable-BCE-with-logits sum over 20 classes, one-hot via direct gather
__device__ __forceinline__ float cls_term(const float4* cp, const float* cls_f,
                                          size_t ba, int lab)
{
    float s2 = 0.f;
    #pragma unroll
    for (int q = 0; q < 5; ++q) {
        float4 v = cp[q];
        s2 += fmaxf(v.x, 0.f) + softplus_negabs(v.x);
        s2 += fmaxf(v.y, 0.f) + softplus_negabs(v.y);
        s2 += fmaxf(v.z, 0.f) + softplus_negabs(v.z);
        s2 += fmaxf(v.w, 0.f) + softplus_negabs(v.w);
    }
    float xl = cls_f[ba * 20 + (size_t)lab];
    return (s2 - xl) * (1.f / 20.f);
}

// giou + 0.5*l1 (loss value only -> fast rcp ok)
__device__ __forceinline__ float bterm_at(float4 pb, float4 mb)
{
    float x1 = fmaxf(pb.x, mb.x), y1 = fmaxf(pb.y, mb.y);
    float x2 = fminf(pb.z, mb.z), y2 = fminf(pb.w, mb.w);
    float inter = fmaxf(x2 - x1, 0.f) * fmaxf(y2 - y1, 0.f);
    float pa1 = (pb.z - pb.x) * (pb.w - pb.y);
    float pa2 = (mb.z - mb.x) * (mb.w - mb.y);
    float uni = pa1 + pa2 - inter;
    float iou = inter * RCPF(uni + EPSF);
    float ex1 = fminf(pb.x, mb.x), ey1 = fminf(pb.y, mb.y);
    float ex2 = fmaxf(pb.z, mb.z), ey2 = fmaxf(pb.w, mb.w);
    float enc = (ex2 - ex1) * (ey2 - ey1);
    float giou = iou - (enc - uni) * RCPF(enc + EPSF);
    float l1 = 0.25f * (fabsf(pb.x - mb.x) + fabsf(pb.y - mb.y) +
                        fabsf(pb.z - mb.z) + fabsf(pb.w - mb.w));
    return (1.f - giou) + 0.5f * l1;
}

// K0: pack target boxes + area + candidate-test scalar (32B stride).
__global__ __launch_bounds__(1024) void k0_pack(
    const float4* __restrict__ tboxes, float* __restrict__ pack)
{
    const int i = threadIdx.x;              // 0..1023 = B*T
    float4 t = tboxes[i];
    float ar = (t.z - t.x) * (t.w - t.y);
    float* p = pack + i * 8;
    p[0] = t.x; p[1] = t.y; p[2] = t.z; p[3] = t.w;
    p[4] = ar;
    p[5] = 0.2493f * (ar + EPSF);           // candidate test rhs
    p[6] = 0.f; p[7] = 0.f;
}

// K1: 12-op hot loop -> candidate bitmask; exact two-phase 32-bit resolution;
//     full fused losses under pos:=thr (forced-only patched in k2).
__global__ __launch_bounds__(256) void k1_main(
    const float4* __restrict__ anchors,
    const float4* __restrict__ bbox,
    const float*  __restrict__ conf,
    const float4* __restrict__ cls,       // 20 floats/anchor = 5 x float4
    const float*  __restrict__ pack,
    const int*    __restrict__ tlabels,
    unsigned long long* __restrict__ keys,
    unsigned char* __restrict__ code,
    float4* __restrict__ partials)
{
    __shared__ float4 tb[T_N];
    __shared__ float  ta[T_N];
    __shared__ int    tl[T_N];
    __shared__ unsigned int slot_hi[T_N];
    __shared__ unsigned int slot_lo[T_N];
    const int b   = blockIdx.y;
    const int tid = threadIdx.x;
    const float* pk = pack + (size_t)b * T_N * 8;
    if (tid < T_N) {
        const float* q = pk + tid * 8;
        tb[tid] = make_float4(q[0], q[1], q[2], q[3]);
        ta[tid] = q[4];
        tl[tid] = tlabels[b * T_N + tid];
        slot_hi[tid] = 0u;
        slot_lo[tid] = 0u;
    }
    __syncthreads();

    const int a = blockIdx.x * 256 + tid;
    const float4 an = anchors[a];
    const float a1 = (an.z - an.x) * (an.w - an.y);
    const float npa = -0.2493f * a1;            // hoisted per-anchor
    const unsigned int lo = ~(unsigned int)a;   // smaller idx -> larger lo

    // hot loop: candidate bit only.  test: 1.2493*inter - 0.2493*a1 >= 0.2493*(ta+eps)
    //  <=> inter >= 0.19955*(a1+ta+eps)  — strict superset of iou>=0.25; exact
    //  winners are recomputed from the mask, empty targets hit the exact fallback.
    unsigned int mlo = 0u, mhi = 0u;
    #pragma unroll 8
    for (int s = 0; s < 32; ++s) {
        const float* q = pk + s * 8;            // uniform -> s_load
        float x1 = fmaxf(an.x, q[0]), y1 = fmaxf(an.y, q[1]);
        float x2 = fminf(an.z, q[2]), y2 = fminf(an.w, q[3]);
        float inter = fmaxf(x2 - x1, 0.f) * fmaxf(y2 - y1, 0.f);
        mlo = mlo + mlo + ((fmaf(1.2493f, inter, npa) >= q[5]) ? 1u : 0u); // bit 31-s
    }
    #pragma unroll 8
    for (int s = 32; s < 64; ++s) {
        const float* q = pk + s * 8;
        float x1 = fmaxf(an.x, q[0]), y1 = fmaxf(an.y, q[1]);
        float x2 = fminf(an.z, q[2]), y2 = fminf(an.w, q[3]);
        float inter = fmaxf(x2 - x1, 0.f) * fmaxf(y2 - y1, 0.f);
        mhi = mhi + mhi + ((fmaf(1.2493f, inter, npa) >= q[5]) ? 1u : 0u); // bit 63-s
    }

    // pass 1: exact iou per candidate (ascending s = first-max), block max bits
    unsigned int bb = 0u; int bt = 0;
    {
        unsigned int w = mlo;
        while (w) {
            int z = __builtin_clz(w); w &= ~(0x80000000u >> z);
            float iou = iou_at(an, a1, tb[z].x, tb[z].y, tb[z].z, tb[z].w, ta[z]);
            unsigned int u = __float_as_uint(iou);
            if (u > bb) { bb = u; bt = z; }
            atomicMax(&slot_hi[z], u);          // native ds_max_u32
        }
        w = mhi;
        while (w) {
            int z = __builtin_clz(w); w &= ~(0x80000000u >> z);
            int s = 32 + z;
            float iou = iou_at(an, a1, tb[s].x, tb[s].y, tb[s].z, tb[s].w, ta[s]);
            unsigned int u = __float_as_uint(iou);
            if (u > bb) { bb = u; bt = s; }
            atomicMax(&slot_hi[s], u);
        }
    }
    __syncthreads();
    // pass 2: among max-achievers, min anchor index (first-max ties)
    {
        unsigned int w = mlo;
        while (w) {
            int z = __builtin_clz(w); w &= ~(0x80000000u >> z);
            float iou = iou_at(an, a1, tb[z].x, tb[z].y, tb[z].z, tb[z].w, ta[z]);
            if (__float_as_uint(iou) == slot_hi[z]) atomicMax(&slot_lo[z], lo);
        }
        w = mhi;
        while (w) {
            int z = __builtin_clz(w); w &= ~(0x80000000u >> z);
            int s = 32 + z;
            float iou = iou_at(an, a1, tb[s].x, tb[s].y, tb[s].z, tb[s].w, ta[s]);
            if (__float_as_uint(iou) == slot_hi[s]) atomicMax(&slot_lo[s], lo);
        }
    }

    const bool thr = (bb >= 0x3F000000u);       // max quotient >= 0.5f
    const size_t ba = (size_t)b * A_N + a;
    code[ba] = (unsigned char)(bt | (thr ? 128 : 0));

    const float cterm = conf_term(conf[ba], thr);

    float bterm = 0.f, clterm = 0.f;
    if (thr) {                                  // exec-masked once per wave
        bterm  = bterm_at(bbox[ba], tb[bt]);
        clterm = cls_term(cls + ba * 5, (const float*)cls, ba, tl[bt] - 1);
    }

    float r0 = cterm, r1 = thr ? 1.f : 0.f, r2 = bterm, r3 = clterm;
    #pragma unroll
    for (int off = 32; off; off >>= 1) {
        r0 += __shfl_down(r0, off, 64);
        r1 += __shfl_down(r1, off, 64);
        r2 += __shfl_down(r2, off, 64);
        r3 += __shfl_down(r3, off, 64);
    }
    __shared__ float4 red[4];
    const int wv = tid >> 6;
    if ((tid & 63) == 0) red[wv] = make_float4(r0, r1, r2, r3);
    __syncthreads();   // also fences pass-2 atomics before slot readback
    if (tid == 0) {
        float4 v;
        v.x = red[0].x + red[1].x + red[2].x + red[3].x;
        v.y = red[0].y + red[1].y + red[2].y + red[3].y;
        v.z = red[0].z + red[1].z + red[2].z + red[3].z;
        v.w = red[0].w + red[1].w + red[2].w + red[3].w;
        partials[(size_t)b * NB + blockIdx.x] = v;
    }
    if (tid < T_N)
        keys[(((size_t)b * NB + blockIdx.x) << 6) | tid] =
            ((unsigned long long)slot_hi[tid] << 32) | (unsigned long long)slot_lo[tid];
}

// K2: per image — winners + exact fallback + forced-only corrections +
//     per-image loss finalize. One block per image.
__global__ __launch_bounds__(1024) void k2_all(
    const unsigned long long* __restrict__ keys,
    const float4* __restrict__ anchors,
    const float4* __restrict__ bbox,
    const float*  __restrict__ conf,
    const float4* __restrict__ cls,
    const float*  __restrict__ pack,
    const int*    __restrict__ tlabels,
    const unsigned char* __restrict__ code,
    const float4* __restrict__ partials,
    float* __restrict__ lossImg)
{
    __shared__ unsigned long long sh[16][64];
    __shared__ unsigned long long sw[16];
    __shared__ unsigned int winner[64];
    __shared__ int emptyList[64];
    __shared__ int nEmpty;
    __shared__ float4 corr;
    __shared__ float4 redf[4];
    const int b = blockIdx.x, tid = threadIdx.x;
    const int t = tid & 63, g = tid >> 6;
    const float* pk = pack + (size_t)b * T_N * 8;
    if (tid == 0) nEmpty = 0;

    unsigned long long K = 0ull;
    #pragma unroll 4
    for (int i = 0; i < 16; ++i) {
        unsigned long long k = keys[(((size_t)b * NB + (g * 16 + i)) << 6) | t];
        if (k > K) K = k;
    }
    sh[g][t] = K;
    __syncthreads();
    if (tid < 64) {
        unsigned long long m = sh[0][tid];
        #pragma unroll
        for (int g2 = 1; g2 < 16; ++g2) if (sh[g2][tid] > m) m = sh[g2][tid];
        unsigned int lo32 = (unsigned int)(m & 0xFFFFFFFFull);
        if (lo32 != 0u) winner[tid] = ~lo32;
        else { int i = atomicAdd(&nEmpty, 1); emptyList[i] = tid; }
    }
    __syncthreads();

    const int ne = nEmpty;            // normally 0
    for (int e = 0; e < ne; ++e) {
        const int tt = emptyList[e];
        const float* q = pk + tt * 8;
        const float tx1 = q[0], ty1 = q[1], tx2 = q[2], ty2 = q[3], tar = q[4];
        unsigned long long bk = 0ull;
        for (int i = tid; i < A_N; i += 1024) {
            float4 an = anchors[i];
            float a1 = (an.z - an.x) * (an.w - an.y);
            float iou = iou_at(an, a1, tx1, ty1, tx2, ty2, tar);
            unsigned long long key = ((unsigned long long)__float_as_uint(iou) << 32)
                                   | (unsigned long long)(~(unsigned int)i);
            if (key > bk) bk = key;
        }
        #pragma unroll
        for (int off = 32; off; off >>= 1) {
            unsigned long long o = __shfl_down(bk, off, 64);
            if (o > bk) bk = o;
        }
        if ((tid & 63) == 0) sw[g] = bk;
        __syncthreads();
        if (tid == 0) {
            unsigned long long m = sw[0];
            #pragma unroll
            for (int i = 1; i < 16; ++i) if (sw[i] > m) m = sw[i];
            winner[tt] = ~(unsigned int)(m & 0xFFFFFFFFull);
        }
        __syncthreads();
    }

    // corrections: first wave, dedupe winners (lowest target owns), exact
    // row-argmax recompute for matched target.
    if (tid < 64) {
        const unsigned int wa = winner[tid];
        bool owner = true;
        for (int k = 0; k < 64; ++k) {
            unsigned int o = __shfl(wa, k, 64);
            if (k < tid && o == wa) owner = false;
        }
        const size_t ba = (size_t)b * A_N + wa;
        float d0 = 0.f, d1 = 0.f, d2 = 0.f, d3 = 0.f;
        if (owner && (code[ba] & 128) == 0) {
            const float4 aw = anchors[wa];
            const float aw1 = (aw.z - aw.x) * (aw.w - aw.y);
            unsigned int bb = 0u; int bt = 0;
            for (int s = 0; s < T_N; ++s) {
                const float* q = pk + s * 8;
                float iou = iou_at(aw, aw1, q[0], q[1], q[2], q[3], q[4]);
                unsigned int u = __float_as_uint(iou);
                if (u > bb) { bb = u; bt = s; }
            }
            const float p = conf[ba];
            d0 = conf_term(p, true) - conf_term(p, false);   // f0 cancels k1's term
            d1 = 1.f;
            const float* qb = pk + bt * 8;
            d2 = bterm_at(bbox[ba], make_float4(qb[0], qb[1], qb[2], qb[3]));
            d3 = cls_term(cls + ba * 5, (const float*)cls, ba,
                          tlabels[b * T_N + bt] - 1);
        }
        #pragma unroll
        for (int off = 32; off; off >>= 1) {
            d0 += __shfl_down(d0, off, 64);
            d1 += __shfl_down(d1, off, 64);
            d2 += __shfl_down(d2, off, 64);
            d3 += __shfl_down(d3, off, 64);
        }
        if (tid == 0) corr = make_float4(d0, d1, d2, d3);
    }
    __syncthreads();

    // finalize: sum this image's 256 float4 partials + corr -> per-image losses
    if (tid < 256) {
        float4 v = partials[(size_t)b * NB + tid];
        #pragma unroll
        for (int off = 32; off; off >>= 1) {
            v.x += __shfl_down(v.x, off, 64);
            v.y += __shfl_down(v.y, off, 64);
            v.z += __shfl_down(v.z, off, 64);
            v.w += __shfl_down(v.w, off, 64);
        }
        if ((tid & 63) == 0) redf[tid >> 6] = v;
    }
    __syncthreads();
    if (tid == 0) {
        float s0 = redf[0].x + redf[1].x + redf[2].x + redf[3].x + corr.x;
        float s1 = redf[0].y + redf[1].y + redf[2].y + redf[3].y + corr.y;
        float s2 = redf[0].z + redf[1].z + redf[2].z + redf[3].z + corr.z;
        float s3 = redf[0].w + redf[1].w + redf[2].w + redf[3].w + corr.w;
        float npos = fmaxf(s1, 1.f);
        lossImg[b * 3 + 0] = s0 * (1.f / (float)A_N);
        lossImg[b * 3 + 1] = s2 / npos;
        lossImg[b * 3 + 2] = s3 / npos;
    }
}

// K4: batch means -> 4 outputs. One wave.
__global__ __launch_bounds__(64) void k4_final(
    const float* __restrict__ lossImg, float* __restrict__ out)
{
    const int lane = threadIdx.x;
    float c = 0.f, bm = 0.f, l = 0.f;
    if (lane < B_N) {
        c  = lossImg[lane * 3 + 0];
        bm = lossImg[lane * 3 + 1];
        l  = lossImg[lane * 3 + 2];
    }
    #pragma unroll
    for (int off = 8; off; off >>= 1) {
        c  += __shfl_down(c,  off, 64);
        bm += __shfl_down(bm, off, 64);
        l  += __shfl_down(l,  off, 64);
    }
    if (lane == 0) {
        c *= (1.f / 16.f); bm *= (1.f / 16.f); l *= (1.f / 16.f);
        out[0] = c + bm + l;
        out[1] = c;
        out[2] = bm;
        out[3] = l;
    }
}

extern "C" void kernel_launch(void* const* d_in, const int* in_sizes, int n_in,
                              void* d_out, int out_size, void* d_ws, size_t ws_size,
                              hipStream_t stream)
{
    const float4* bbox    = (const float4*)d_in[0];
    const float*  conf    = (const float*) d_in[1];
    const float4* cls     = (const float4*)d_in[2];
    const float4* anchors = (const float4*)d_in[3];
    const float4* tboxes  = (const float4*)d_in[4];
    const int*    tlabels = (const int*)   d_in[5];
    float* out = (float*)d_out;

    char* ws = (char*)d_ws;
    unsigned long long* keys  = (unsigned long long*)ws;                   // 2 MiB
    unsigned char*      code  = (unsigned char*)(ws + (2u << 20));         // 1 MiB
    float4*             partials = (float4*)(ws + (3u << 20));             // 64 KiB
    float*              lossImg  = (float*)(ws + (3u << 20) + (64u << 10));// 192 B
    float*              pack     = (float*)(ws + (3u << 20) + (128u << 10)); // 32 KiB

    k0_pack <<<1, 1024, 0, stream>>>(tboxes, pack);
    k1_main <<<dim3(NB, B_N), 256, 0, stream>>>(anchors, bbox, conf, cls, pack,
                                                tlabels, keys, code, partials);
    k2_all  <<<B_N, 1024, 0, stream>>>(keys, anchors, bbox, conf, cls, pack,
                                       tlabels, code, partials, lossImg);
    k4_final<<<1, 64, 0, stream>>>(lossImg, out);
}

// Round 9
// 64.584 us; speedup vs baseline: 1.8237x; 1.0630x over previous
//
#include <hip/hip_runtime.h>
#include <stdint.h>
#include <math.h>

#define A_N 65536
#define B_N 16
#define T_N 64
#define NB1 (A_N / 512)      // k1 blocks per image = 128 (2 anchors/thread)
#define EPSF 1e-6f
#define LN2F   0.69314718055994531f
#define LOG2EF 1.4426950408889634f

// fast hw ops: v_exp_f32 (2^x), v_log_f32 (log2 x), v_rcp_f32, v_sqrt_f32
#define EXP2F(x) __builtin_amdgcn_exp2f(x)
#define LOG2F(x) __builtin_amdgcn_logf(x)
#define RCPF(x)  __builtin_amdgcn_rcpf(x)
#define SQRTF(x) __builtin_amdgcn_sqrtf(x)

// ---------------------------------------------------------------------------
// Workspace:
//   keys     : B * NB1 * 64 * u64 = 1 MiB   @ 0         (hi=iou bits, lo=~anchor)
//   code     : B * A * u8         = 1 MiB   @ 2 MiB     (bt | thr<<7)
//   partials : B * NB1 * float4   = 32 KiB  @ 3 MiB     (conf, ct, bbox, cls)
//   lossImg  : B * 3 * f32        = 192 B   @ 3 MiB+64K
//   pack     : B * 64 * 8 * f32   = 32 KiB  @ 3 MiB+128K ({x1,y1,x2,y2,area,rhs,..})
// ---------------------------------------------------------------------------

// fast iou (v_rcp: deterministic, ~1-2 ulp vs IEEE quotient).  Used by ALL
// selection paths, so pass1/pass2 bit-equality and key ordering stay
// self-consistent; ulp-level divergence from np flips only exact-tie argmax
// cases, each worth ~1e-4 in the final losses (tolerance 5.9e-2).
__device__ __forceinline__ float iou_fast(float4 an, float a1, float tx1, float ty1,
                                          float tx2, float ty2, float tar)
{
    float x1 = fmaxf(an.x, tx1), y1 = fmaxf(an.y, ty1);
    float x2 = fminf(an.z, tx2), y2 = fminf(an.w, ty2);
    float inter = fmaxf(x2 - x1, 0.f) * fmaxf(y2 - y1, 0.f);
    float ue = ((a1 + tar) - inter) + EPSF;          // np-exact association
    return inter * RCPF(ue);
}

// focal BCE conf term; shared by k1 and corrections so f0 cancels bitwise
__device__ __forceinline__ float conf_term(float p, bool pos)
{
    float u = pos ? p : (1.f - p);
    float w = 1.f - u;
    float bce = -LN2F * LOG2F(u + EPSF);
    float fw = w * SQRTF(w);             // w^1.5
    return bce * fw * 0.5f;              // alpha factor == 0.5
}

__device__ __forceinline__ float softplus_negabs(float x)
{
    float y = EXP2F(fabsf(x) * -LOG2EF);
    return LN2F * LOG2F(1.0f + y);
}

__device__ __forceinline__ float cls_term(const float4* cp, const float* cls_f,
                                          size_t ba, int lab)
{
    float s2 = 0.f;
    #pragma unroll
    for (int q = 0; q < 5; ++q) {
        float4 v = cp[q];
        s2 += fmaxf(v.x, 0.f) + softplus_negabs(v.x);
        s2 += fmaxf(v.y, 0.f) + softplus_negabs(v.y);
        s2 += fmaxf(v.z, 0.f) + softplus_negabs(v.z);
        s2 += fmaxf(v.w, 0.f) + softplus_negabs(v.w);
    }
    float xl = cls_f[ba * 20 + (size_t)lab];
    return (s2 - xl) * (1.f / 20.f);
}

__device__ __forceinline__ float bterm_at(float4 pb, float4 mb)
{
    float x1 = fmaxf(pb.x, mb.x), y1 = fmaxf(pb.y, mb.y);
    float x2 = fminf(pb.z, mb.z), y2 = fminf(pb.w, mb.w);
    float inter = fmaxf(x2 - x1, 0.f) * fmaxf(y2 - y1, 0.f);
    float pa1 = (pb.z - pb.x) * (pb.w - pb.y);
    float pa2 = (mb.z - mb.x) * (mb.w - mb.y);
    float uni = pa1 + pa2 - inter;
    float iou = inter * RCPF(uni + EPSF);
    float ex1 = fminf(pb.x, mb.x), ey1 = fminf(pb.y, mb.y);
    float ex2 = fmaxf(pb.z, mb.z), ey2 = fmaxf(pb.w, mb.w);
    float enc = (ex2 - ex1) * (ey2 - ey1);
    float giou = iou - (enc - uni) * RCPF(enc + EPSF);
    float l1 = 0.25f * (fabsf(pb.x - mb.x) + fabsf(pb.y - mb.y) +
                        fabsf(pb.z - mb.z) + fabsf(pb.w - mb.w));
    return (1.f - giou) + 0.5f * l1;
}

// K0: pack target boxes + area + candidate-test rhs (32B stride).
__global__ __launch_bounds__(1024) void k0_pack(
    const float4* __restrict__ tboxes, float* __restrict__ pack)
{
    const int i = threadIdx.x;              // 0..1023 = B*T
    float4 t = tboxes[i];
    float ar = (t.z - t.x) * (t.w - t.y);
    float* p = pack + i * 8;
    p[0] = t.x; p[1] = t.y; p[2] = t.z; p[3] = t.w;
    p[4] = ar;
    p[5] = 0.2493f * (ar + EPSF);           // candidate test rhs
    p[6] = 0.f; p[7] = 0.f;
}

// pass1: exact-first-max tracking + slot_hi atomicMax; survivor mask out
__device__ __forceinline__ void resolve_p1(
    unsigned int w, int base, float4 an, float a1,
    const float4* tb, const float* ta, unsigned int* slot_hi,
    unsigned int& bb, int& bt, unsigned int& m2)
{
    m2 = 0u;
    while (w) {
        int z = __builtin_clz(w);               // ascending s = first-max
        unsigned int bit = 0x80000000u >> z;
        w &= ~bit;
        int s = base + z;
        float iou = iou_fast(an, a1, tb[s].x, tb[s].y, tb[s].z, tb[s].w, ta[s]);
        unsigned int u = __float_as_uint(iou);
        if (u > bb) { bb = u; bt = s; }
        unsigned int old = atomicMax(&slot_hi[s], u);
        if (u >= old) m2 |= bit;                // running max -> possible winner
    }
}

// pass2: among final-max achievers, max ~anchor (= min anchor index)
__device__ __forceinline__ void resolve_p2(
    unsigned int m2, int base, float4 an, float a1,
    const float4* tb, const float* ta, const unsigned int* slot_hi,
    unsigned int* slot_lo, unsigned int lo)
{
    while (m2) {
        int z = __builtin_clz(m2);
        m2 &= ~(0x80000000u >> z);
        int s = base + z;
        float iou = iou_fast(an, a1, tb[s].x, tb[s].y, tb[s].z, tb[s].w, ta[s]);
        if (__float_as_uint(iou) == slot_hi[s]) atomicMax(&slot_lo[s], lo);
    }
}

// K1: 2 anchors/thread; 12-op/pair hot loop; rcp-iou resolution with
//     survivor-mask pass2; fused losses under pos:=thr.
__global__ __launch_bounds__(256) void k1_main(
    const float4* __restrict__ anchors,
    const float4* __restrict__ bbox,
    const float*  __restrict__ conf,
    const float4* __restrict__ cls,       // 20 floats/anchor = 5 x float4
    const float*  __restrict__ pack,
    const int*    __restrict__ tlabels,
    unsigned long long* __restrict__ keys,
    unsigned char* __restrict__ code,
    float4* __restrict__ partials)
{
    __shared__ float4 tb[T_N];
    __shared__ float  ta[T_N];
    __shared__ int    tl[T_N];
    __shared__ unsigned int slot_hi[T_N];
    __shared__ unsigned int slot_lo[T_N];
    const int b   = blockIdx.y;
    const int tid = threadIdx.x;
    const float* pk = pack + (size_t)b * T_N * 8;
    if (tid < T_N) {
        const float* q = pk + tid * 8;
        tb[tid] = make_float4(q[0], q[1], q[2], q[3]);
        ta[tid] = q[4];
        tl[tid] = tlabels[b * T_N + tid];
        slot_hi[tid] = 0u;
        slot_lo[tid] = 0u;
    }
    __syncthreads();

    const int aA = blockIdx.x * 512 + tid;
    const int aB = aA + 256;
    const float4 anA = anchors[aA];
    const float4 anB = anchors[aB];
    const float arA = (anA.z - anA.x) * (anA.w - anA.y);
    const float arB = (anB.z - anB.x) * (anB.w - anB.y);
    const float npaA = -0.2493f * arA;
    const float npaB = -0.2493f * arB;
    const unsigned int loA = ~(unsigned int)aA;
    const unsigned int loB = ~(unsigned int)aB;

    // hot loop: candidate bit per (anchor,target).  Test:
    //   1.2493*inter - 0.2493*a1 >= 0.2493*(ta+eps)   (superset of iou>=0.25)
    unsigned int mAlo = 0u, mAhi = 0u, mBlo = 0u, mBhi = 0u;
    #pragma unroll 8
    for (int s = 0; s < 32; ++s) {
        const float* q = pk + s * 8;            // wave-uniform -> s_load
        float xA1 = fmaxf(anA.x, q[0]), yA1 = fmaxf(anA.y, q[1]);
        float xA2 = fminf(anA.z, q[2]), yA2 = fminf(anA.w, q[3]);
        float iA = fmaxf(xA2 - xA1, 0.f) * fmaxf(yA2 - yA1, 0.f);
        mAlo = mAlo + mAlo + ((fmaf(1.2493f, iA, npaA) >= q[5]) ? 1u : 0u);
        float xB1 = fmaxf(anB.x, q[0]), yB1 = fmaxf(anB.y, q[1]);
        float xB2 = fminf(anB.z, q[2]), yB2 = fminf(anB.w, q[3]);
        float iB = fmaxf(xB2 - xB1, 0.f) * fmaxf(yB2 - yB1, 0.f);
        mBlo = mBlo + mBlo + ((fmaf(1.2493f, iB, npaB) >= q[5]) ? 1u : 0u);
    }
    #pragma unroll 8
    for (int s = 32; s < 64; ++s) {
        const float* q = pk + s * 8;
        float xA1 = fmaxf(anA.x, q[0]), yA1 = fmaxf(anA.y, q[1]);
        float xA2 = fminf(anA.z, q[2]), yA2 = fminf(anA.w, q[3]);
        float iA = fmaxf(xA2 - xA1, 0.f) * fmaxf(yA2 - yA1, 0.f);
        mAhi = mAhi + mAhi + ((fmaf(1.2493f, iA, npaA) >= q[5]) ? 1u : 0u);
        float xB1 = fmaxf(anB.x, q[0]), yB1 = fmaxf(anB.y, q[1]);
        float xB2 = fminf(anB.z, q[2]), yB2 = fminf(anB.w, q[3]);
        float iB = fmaxf(xB2 - xB1, 0.f) * fmaxf(yB2 - yB1, 0.f);
        mBhi = mBhi + mBhi + ((fmaf(1.2493f, iB, npaB) >= q[5]) ? 1u : 0u);
    }

    unsigned int bbA = 0u, bbB = 0u; int btA = 0, btB = 0;
    unsigned int m2Alo, m2Ahi, m2Blo, m2Bhi;
    resolve_p1(mAlo,  0, anA, arA, tb, ta, slot_hi, bbA, btA, m2Alo);
    resolve_p1(mAhi, 32, anA, arA, tb, ta, slot_hi, bbA, btA, m2Ahi);
    resolve_p1(mBlo,  0, anB, arB, tb, ta, slot_hi, bbB, btB, m2Blo);
    resolve_p1(mBhi, 32, anB, arB, tb, ta, slot_hi, bbB, btB, m2Bhi);
    __syncthreads();
    resolve_p2(m2Alo,  0, anA, arA, tb, ta, slot_hi, slot_lo, loA);
    resolve_p2(m2Ahi, 32, anA, arA, tb, ta, slot_hi, slot_lo, loA);
    resolve_p2(m2Blo,  0, anB, arB, tb, ta, slot_hi, slot_lo, loB);
    resolve_p2(m2Bhi, 32, anB, arB, tb, ta, slot_hi, slot_lo, loB);

    const bool thrA = (bbA >= 0x3F000000u);     // max iou >= 0.5
    const bool thrB = (bbB >= 0x3F000000u);
    const size_t baA = (size_t)b * A_N + aA;
    const size_t baB = (size_t)b * A_N + aB;
    code[baA] = (unsigned char)(btA | (thrA ? 128 : 0));
    code[baB] = (unsigned char)(btB | (thrB ? 128 : 0));

    float r0 = conf_term(conf[baA], thrA) + conf_term(conf[baB], thrB);
    float r1 = (thrA ? 1.f : 0.f) + (thrB ? 1.f : 0.f);
    float r2 = 0.f, r3 = 0.f;
    if (thrA) {
        r2 += bterm_at(bbox[baA], tb[btA]);
        r3 += cls_term(cls + baA * 5, (const float*)cls, baA, tl[btA] - 1);
    }
    if (thrB) {
        r2 += bterm_at(bbox[baB], tb[btB]);
        r3 += cls_term(cls + baB * 5, (const float*)cls, baB, tl[btB] - 1);
    }

    #pragma unroll
    for (int off = 32; off; off >>= 1) {
        r0 += __shfl_down(r0, off, 64);
        r1 += __shfl_down(r1, off, 64);
        r2 += __shfl_down(r2, off, 64);
        r3 += __shfl_down(r3, off, 64);
    }
    __shared__ float4 red[4];
    const int wv = tid >> 6;
    if ((tid & 63) == 0) red[wv] = make_float4(r0, r1, r2, r3);
    __syncthreads();   // also fences pass-2 atomics before slot readback
    if (tid == 0) {
        float4 v;
        v.x = red[0].x + red[1].x + red[2].x + red[3].x;
        v.y = red[0].y + red[1].y + red[2].y + red[3].y;
        v.z = red[0].z + red[1].z + red[2].z + red[3].z;
        v.w = red[0].w + red[1].w + red[2].w + red[3].w;
        partials[(size_t)b * NB1 + blockIdx.x] = v;
    }
    if (tid < T_N)
        keys[(((size_t)b * NB1 + blockIdx.x) << 6) | tid] =
            ((unsigned long long)slot_hi[tid] << 32) | (unsigned long long)slot_lo[tid];
}

// K2: per image — winners + exact fallback + forced-only corrections +
//     per-image loss finalize. One block per image.
__global__ __launch_bounds__(1024) void k2_all(
    const unsigned long long* __restrict__ keys,
    const float4* __restrict__ anchors,
    const float4* __restrict__ bbox,
    const float*  __restrict__ conf,
    const float4* __restrict__ cls,
    const float*  __restrict__ pack,
    const int*    __restrict__ tlabels,
    const unsigned char* __restrict__ code,
    const float4* __restrict__ partials,
    float* __restrict__ lossImg)
{
    __shared__ unsigned long long sh[16][64];
    __shared__ unsigned long long sw[16];
    __shared__ unsigned int winner[64];
    __shared__ int emptyList[64];
    __shared__ int nEmpty;
    __shared__ float4 corr;
    __shared__ float4 redf[2];
    const int b = blockIdx.x, tid = threadIdx.x;
    const int t = tid & 63, g = tid >> 6;
    const float* pk = pack + (size_t)b * T_N * 8;
    if (tid == 0) nEmpty = 0;

    unsigned long long K = 0ull;
    #pragma unroll
    for (int i = 0; i < 8; ++i) {
        unsigned long long k = keys[(((size_t)b * NB1 + (g * 8 + i)) << 6) | t];
        if (k > K) K = k;
    }
    sh[g][t] = K;
    __syncthreads();
    if (tid < 64) {
        unsigned long long m = sh[0][tid];
        #pragma unroll
        for (int g2 = 1; g2 < 16; ++g2) if (sh[g2][tid] > m) m = sh[g2][tid];
        unsigned int lo32 = (unsigned int)(m & 0xFFFFFFFFull);
        if (lo32 != 0u) winner[tid] = ~lo32;
        else { int i = atomicAdd(&nEmpty, 1); emptyList[i] = tid; }
    }
    __syncthreads();

    const int ne = nEmpty;            // normally 0
    for (int e = 0; e < ne; ++e) {
        const int tt = emptyList[e];
        const float* q = pk + tt * 8;
        const float tx1 = q[0], ty1 = q[1], tx2 = q[2], ty2 = q[3], tar = q[4];
        unsigned long long bk = 0ull;
        for (int i = tid; i < A_N; i += 1024) {
            float4 an = anchors[i];
            float a1 = (an.z - an.x) * (an.w - an.y);
            float iou = iou_fast(an, a1, tx1, ty1, tx2, ty2, tar);
            unsigned long long key = ((unsigned long long)__float_as_uint(iou) << 32)
                                   | (unsigned long long)(~(unsigned int)i);
            if (key > bk) bk = key;
        }
        #pragma unroll
        for (int off = 32; off; off >>= 1) {
            unsigned long long o = __shfl_down(bk, off, 64);
            if (o > bk) bk = o;
        }
        if ((tid & 63) == 0) sw[g] = bk;
        __syncthreads();
        if (tid == 0) {
            unsigned long long m = sw[0];
            #pragma unroll
            for (int i = 1; i < 16; ++i) if (sw[i] > m) m = sw[i];
            winner[tt] = ~(unsigned int)(m & 0xFFFFFFFFull);
        }
        __syncthreads();
    }

    // corrections: first wave, dedupe winners (lowest target owns), exact
    // row-argmax recompute for matched target.
    if (tid < 64) {
        const unsigned int wa = winner[tid];
        bool owner = true;
        for (int k = 0; k < 64; ++k) {
            unsigned int o = __shfl(wa, k, 64);
            if (k < tid && o == wa) owner = false;
        }
        const size_t ba = (size_t)b * A_N + wa;
        float d0 = 0.f, d1 = 0.f, d2 = 0.f, d3 = 0.f;
        if (owner && (code[ba] & 128) == 0) {
            const float4 aw = anchors[wa];
            const float aw1 = (aw.z - aw.x) * (aw.w - aw.y);
            unsigned int bb = 0u; int bt = 0;
            for (int s = 0; s < T_N; ++s) {
                const float* q = pk + s * 8;
                float iou = iou_fast(aw, aw1, q[0], q[1], q[2], q[3], q[4]);
                unsigned int u = __float_as_uint(iou);
                if (u > bb) { bb = u; bt = s; }
            }
            const float p = conf[ba];
            d0 = conf_term(p, true) - conf_term(p, false);   // f0 cancels k1's term
            d1 = 1.f;
            const float* qb = pk + bt * 8;
            d2 = bterm_at(bbox[ba], make_float4(qb[0], qb[1], qb[2], qb[3]));
            d3 = cls_term(cls + ba * 5, (const float*)cls, ba,
                          tlabels[b * T_N + bt] - 1);
        }
        #pragma unroll
        for (int off = 32; off; off >>= 1) {
            d0 += __shfl_down(d0, off, 64);
            d1 += __shfl_down(d1, off, 64);
            d2 += __shfl_down(d2, off, 64);
            d3 += __shfl_down(d3, off, 64);
        }
        if (tid == 0) corr = make_float4(d0, d1, d2, d3);
    }
    __syncthreads();

    // finalize: sum this image's 128 float4 partials + corr
    if (tid < NB1) {
        float4 v = partials[(size_t)b * NB1 + tid];
        #pragma unroll
        for (int off = 32; off; off >>= 1) {
            v.x += __shfl_down(v.x, off, 64);
            v.y += __shfl_down(v.y, off, 64);
            v.z += __shfl_down(v.z, off, 64);
            v.w += __shfl_down(v.w, off, 64);
        }
        if ((tid & 63) == 0) redf[tid >> 6] = v;
    }
    __syncthreads();
    if (tid == 0) {
        float s0 = redf[0].x + redf[1].x + corr.x;
        float s1 = redf[0].y + redf[1].y + corr.y;
        float s2 = redf[0].z + redf[1].z + corr.z;
        float s3 = redf[0].w + redf[1].w + corr.w;
        float npos = fmaxf(s1, 1.f);
        lossImg[b * 3 + 0] = s0 * (1.f / (float)A_N);
        lossImg[b * 3 + 1] = s2 / npos;
        lossImg[b * 3 + 2] = s3 / npos;
    }
}

// K4: batch means -> 4 outputs. One wave.
__global__ __launch_bounds__(64) void k4_final(
    const float* __restrict__ lossImg, float* __restrict__ out)
{
    const int lane = threadIdx.x;
    float c = 0.f, bm = 0.f, l = 0.f;
    if (lane < B_N) {
        c  = lossImg[lane * 3 + 0];
        bm = lossImg[lane * 3 + 1];
        l  = lossImg[lane * 3 + 2];
    }
    #pragma unroll
    for (int off = 8; off; off >>= 1) {
        c  += __shfl_down(c,  off, 64);
        bm += __shfl_down(bm, off, 64);
        l  += __shfl_down(l,  off, 64);
    }
    if (lane == 0) {
        c *= (1.f / 16.f); bm *= (1.f / 16.f); l *= (1.f / 16.f);
        out[0] = c + bm + l;
        out[1] = c;
        out[2] = bm;
        out[3] = l;
    }
}

extern "C" void kernel_launch(void* const* d_in, const int* in_sizes, int n_in,
                              void* d_out, int out_size, void* d_ws, size_t ws_size,
                              hipStream_t stream)
{
    const float4* bbox    = (const float4*)d_in[0];
    const float*  conf    = (const float*) d_in[1];
    const float4* cls     = (const float4*)d_in[2];
    const float4* anchors = (const float4*)d_in[3];
    const float4* tboxes  = (const float4*)d_in[4];
    const int*    tlabels = (const int*)   d_in[5];
    float* out = (float*)d_out;

    char* ws = (char*)d_ws;
    unsigned long long* keys  = (unsigned long long*)ws;                   // 1 MiB
    unsigned char*      code  = (unsigned char*)(ws + (2u << 20));         // 1 MiB
    float4*             partials = (float4*)(ws + (3u << 20));             // 32 KiB
    float*              lossImg  = (float*)(ws + (3u << 20) + (64u << 10));// 192 B
    float*              pack     = (float*)(ws + (3u << 20) + (128u << 10)); // 32 KiB

    k0_pack <<<1, 1024, 0, stream>>>(tboxes, pack);
    k1_main <<<dim3(NB1, B_N), 256, 0, stream>>>(anchors, bbox, conf, cls, pack,
                                                 tlabels, keys, code, partials);
    k2_all  <<<B_N, 1024, 0, stream>>>(keys, anchors, bbox, conf, cls, pack,
                                       tlabels, code, partials, lossImg);
    k4_final<<<1, 64, 0, stream>>>(lossImg, out);
}

// Round 10
// 57.958 us; speedup vs baseline: 2.0322x; 1.1143x over previous
//
#include <hip/hip_runtime.h>
#include <stdint.h>
#include <math.h>

#define A_N 65536
#define B_N 16
#define T_N 64
#define NB  (A_N / 256)      // k1 blocks per image = 256 (1 anchor/thread)
#define EPSF 1e-6f
#define LN2F   0.69314718055994531f
#define LOG2EF 1.4426950408889634f

// fast hw ops: v_exp_f32 (2^x), v_log_f32 (log2 x), v_rcp_f32, v_sqrt_f32
#define EXP2F(x) __builtin_amdgcn_exp2f(x)
#define LOG2F(x) __builtin_amdgcn_logf(x)
#define RCPF(x)  __builtin_amdgcn_rcpf(x)
#define SQRTF(x) __builtin_amdgcn_sqrtf(x)

// ---------------------------------------------------------------------------
// Workspace:
//   keys     : B * NB * 64 * u64 = 2 MiB   @ 0          (hi=iou bits, lo=~anchor)
//   code     : B * A * u8        = 1 MiB   @ 2 MiB      (bt | thr<<7)
//   partials : B * NB * float4   = 64 KiB  @ 3 MiB      (conf, ct, bbox, cls)
//   lossImg  : B * 3 * f32       = 192 B   @ 3 MiB+64K
//   done     : u32               = 4 B     @ 3 MiB+64K+256  (reset by k1)
// ---------------------------------------------------------------------------

// fast iou (v_rcp: deterministic per pair; ulp-level vs np flips only exact
// ties, each worth ~1e-4 in final losses vs 5.9e-2 tolerance).
__device__ __forceinline__ float iou_fast(float4 an, float a1, float4 t4, float tar)
{
    float x1 = fmaxf(an.x, t4.x), y1 = fmaxf(an.y, t4.y);
    float x2 = fminf(an.z, t4.z), y2 = fminf(an.w, t4.w);
    float inter = fmaxf(x2 - x1, 0.f) * fmaxf(y2 - y1, 0.f);
    float ue = ((a1 + tar) - inter) + EPSF;          // np-exact association
    return inter * RCPF(ue);
}

// focal BCE conf term; shared by k1 and corrections so f0 cancels bitwise
__device__ __forceinline__ float conf_term(float p, bool pos)
{
    float u = pos ? p : (1.f - p);
    float w = 1.f - u;
    float bce = -LN2F * LOG2F(u + EPSF);
    float fw = w * SQRTF(w);             // w^1.5
    return bce * fw * 0.5f;              // alpha factor == 0.5
}

__device__ __forceinline__ float softplus_negabs(float x)
{
    float y = EXP2F(fabsf(x) * -LOG2EF);
    return LN2F * LOG2F(1.0f + y);
}

__device__ __forceinline__ float cls_term(const float4* cp, const float* cls_f,
                                          size_t ba, int lab)
{
    float s2 = 0.f;
    #pragma unroll
    for (int q = 0; q < 5; ++q) {
        float4 v = cp[q];
        s2 += fmaxf(v.x, 0.f) + softplus_negabs(v.x);
        s2 += fmaxf(v.y, 0.f) + softplus_negabs(v.y);
        s2 += fmaxf(v.z, 0.f) + softplus_negabs(v.z);
        s2 += fmaxf(v.w, 0.f) + softplus_negabs(v.w);
    }
    float xl = cls_f[ba * 20 + (size_t)lab];
    return (s2 - xl) * (1.f / 20.f);
}

__device__ __forceinline__ float bterm_at(float4 pb, float4 mb)
{
    float x1 = fmaxf(pb.x, mb.x), y1 = fmaxf(pb.y, mb.y);
    float x2 = fminf(pb.z, mb.z), y2 = fminf(pb.w, mb.w);
    float inter = fmaxf(x2 - x1, 0.f) * fmaxf(y2 - y1, 0.f);
    float pa1 = (pb.z - pb.x) * (pb.w - pb.y);
    float pa2 = (mb.z - mb.x) * (mb.w - mb.y);
    float uni = pa1 + pa2 - inter;
    float iou = inter * RCPF(uni + EPSF);
    float ex1 = fminf(pb.x, mb.x), ey1 = fminf(pb.y, mb.y);
    float ex2 = fmaxf(pb.z, mb.z), ey2 = fmaxf(pb.w, mb.w);
    float enc = (ex2 - ex1) * (ey2 - ey1);
    float giou = iou - (enc - uni) * RCPF(enc + EPSF);
    float l1 = 0.25f * (fabsf(pb.x - mb.x) + fabsf(pb.y - mb.y) +
                        fabsf(pb.z - mb.z) + fabsf(pb.w - mb.w));
    return (1.f - giou) + 0.5f * l1;
}

// pass1: first-max tracking + slot_hi atomicMax; survivor mask out
__device__ __forceinline__ void resolve_p1(
    unsigned int w, int base, float4 an, float a1,
    const float4* tb, const float* ta, unsigned int* slot_hi,
    unsigned int& bb, int& bt, unsigned int& m2)
{
    m2 = 0u;
    while (w) {
        int z = __builtin_clz(w);               // ascending s = first-max
        unsigned int bit = 0x80000000u >> z;
        w &= ~bit;
        int s = base + z;
        float iou = iou_fast(an, a1, tb[s], ta[s]);
        unsigned int u = __float_as_uint(iou);
        if (u > bb) { bb = u; bt = s; }
        unsigned int old = atomicMax(&slot_hi[s], u);
        if (u >= old) m2 |= bit;                // running max -> possible winner
    }
}

// pass2: among final-max achievers, max ~anchor (= min anchor index)
__device__ __forceinline__ void resolve_p2(
    unsigned int m2, int base, float4 an, float a1,
    const float4* tb, const float* ta, const unsigned int* slot_hi,
    unsigned int* slot_lo, unsigned int lo)
{
    while (m2) {
        int z = __builtin_clz(m2);
        m2 &= ~(0x80000000u >> z);
        int s = base + z;
        float iou = iou_fast(an, a1, tb[s], ta[s]);
        if (__float_as_uint(iou) == slot_hi[s]) atomicMax(&slot_lo[s], lo);
    }
}

// K1: per-block LDS target pack (k0 folded in); 14-op/2-ds_read hot loop;
//     rcp-iou resolution with survivor-mask pass2; fused losses under pos:=thr.
__global__ __launch_bounds__(256) void k1_main(
    const float4* __restrict__ anchors,
    const float4* __restrict__ bbox,
    const float*  __restrict__ conf,
    const float4* __restrict__ cls,       // 20 floats/anchor = 5 x float4
    const float4* __restrict__ tboxes,
    const int*    __restrict__ tlabels,
    unsigned long long* __restrict__ keys,
    unsigned char* __restrict__ code,
    float4* __restrict__ partials,
    unsigned int* __restrict__ done)
{
    __shared__ float4 tb[T_N];
    __shared__ float  ta[T_N];
    __shared__ float  rhsv[T_N];
    __shared__ int    tl[T_N];
    __shared__ unsigned int slot_hi[T_N];
    __shared__ unsigned int slot_lo[T_N];
    const int b   = blockIdx.y;
    const int tid = threadIdx.x;
    if (tid < T_N) {
        float4 t = tboxes[b * T_N + tid];
        float ar = (t.z - t.x) * (t.w - t.y);
        tb[tid] = t;
        ta[tid] = ar;
        rhsv[tid] = 0.2493f * (ar + EPSF);      // candidate-test rhs
        tl[tid] = tlabels[b * T_N + tid];
        slot_hi[tid] = 0u;
        slot_lo[tid] = 0u;
    }
    if (tid == 0 && blockIdx.x == 0 && b == 0) *done = 0u;  // reset for k2
    __syncthreads();

    const int a = blockIdx.x * 256 + tid;
    const float4 an = anchors[a];
    const float a1 = (an.z - an.x) * (an.w - an.y);
    const float npa = -0.2493f * a1;
    const unsigned int lo = ~(unsigned int)a;   // smaller idx -> larger lo

    // hot loop: candidate bit only.  Test:
    //   1.2493*inter - 0.2493*a1 >= 0.2493*(ta+eps)   (superset of iou>=0.25)
    unsigned int mlo = 0u, mhi = 0u;
    #pragma unroll 8
    for (int s = 0; s < 32; ++s) {
        float4 t4 = tb[s];                      // ds_read_b128 (broadcast)
        float r  = rhsv[s];                     // ds_read_b32
        float x1 = fmaxf(an.x, t4.x), y1 = fmaxf(an.y, t4.y);
        float x2 = fminf(an.z, t4.z), y2 = fminf(an.w, t4.w);
        float inter = fmaxf(x2 - x1, 0.f) * fmaxf(y2 - y1, 0.f);
        mlo = mlo + mlo + ((fmaf(1.2493f, inter, npa) >= r) ? 1u : 0u); // bit 31-s
    }
    #pragma unroll 8
    for (int s = 32; s < 64; ++s) {
        float4 t4 = tb[s];
        float r  = rhsv[s];
        float x1 = fmaxf(an.x, t4.x), y1 = fmaxf(an.y, t4.y);
        float x2 = fminf(an.z, t4.z), y2 = fminf(an.w, t4.w);
        float inter = fmaxf(x2 - x1, 0.f) * fmaxf(y2 - y1, 0.f);
        mhi = mhi + mhi + ((fmaf(1.2493f, inter, npa) >= r) ? 1u : 0u); // bit 63-s
    }

    unsigned int bb = 0u; int bt = 0;
    unsigned int m2lo, m2hi;
    resolve_p1(mlo,  0, an, a1, tb, ta, slot_hi, bb, bt, m2lo);
    resolve_p1(mhi, 32, an, a1, tb, ta, slot_hi, bb, bt, m2hi);
    __syncthreads();
    resolve_p2(m2lo,  0, an, a1, tb, ta, slot_hi, slot_lo, lo);
    resolve_p2(m2hi, 32, an, a1, tb, ta, slot_hi, slot_lo, lo);

    const bool thr = (bb >= 0x3F000000u);       // max iou >= 0.5
    const size_t ba = (size_t)b * A_N + a;
    code[ba] = (unsigned char)(bt | (thr ? 128 : 0));

    float r0 = conf_term(conf[ba], thr);
    float r2 = 0.f, r3 = 0.f;
    if (thr) {                                  // exec-masked once per wave
        r2 = bterm_at(bbox[ba], tb[bt]);
        r3 = cls_term(cls + ba * 5, (const float*)cls, ba, tl[bt] - 1);
    }
    const float r1 = (float)__popcll(__ballot(thr));   // pos count, no shfl chain

    #pragma unroll
    for (int off = 32; off; off >>= 1) {
        r0 += __shfl_down(r0, off, 64);
        r2 += __shfl_down(r2, off, 64);
        r3 += __shfl_down(r3, off, 64);
    }
    __shared__ float4 red[4];
    const int wv = tid >> 6;
    if ((tid & 63) == 0) red[wv] = make_float4(r0, r1, r2, r3);
    __syncthreads();   // also fences pass-2 atomics before slot readback
    if (tid == 0) {
        float4 v;
        v.x = red[0].x + red[1].x + red[2].x + red[3].x;
        v.y = red[0].y + red[1].y + red[2].y + red[3].y;
        v.z = red[0].z + red[1].z + red[2].z + red[3].z;
        v.w = red[0].w + red[1].w + red[2].w + red[3].w;
        partials[(size_t)b * NB + blockIdx.x] = v;
    }
    if (tid < T_N)
        keys[(((size_t)b * NB + blockIdx.x) << 6) | tid] =
            ((unsigned long long)slot_hi[tid] << 32) | (unsigned long long)slot_lo[tid];
}

// K2: per image — winners + exact fallback + forced-only corrections +
//     per-image finalize; last block averages across images -> out[4].
__global__ __launch_bounds__(1024) void k2_all(
    const unsigned long long* __restrict__ keys,
    const float4* __restrict__ anchors,
    const float4* __restrict__ bbox,
    const float*  __restrict__ conf,
    const float4* __restrict__ cls,
    const float4* __restrict__ tboxes,
    const int*    __restrict__ tlabels,
    const unsigned char* __restrict__ code,
    const float4* __restrict__ partials,
    float* __restrict__ lossImg,
    unsigned int* __restrict__ done,
    float* __restrict__ out)
{
    __shared__ unsigned long long sh[16][64];
    __shared__ unsigned long long sw[16];
    __shared__ float4 tb[T_N];
    __shared__ float  ta[T_N];
    __shared__ unsigned int winner[64];
    __shared__ int emptyList[64];
    __shared__ int nEmpty;
    __shared__ float4 corr;
    __shared__ float4 redf[4];
    __shared__ int lastFlag;
    const int b = blockIdx.x, tid = threadIdx.x;
    const int t = tid & 63, g = tid >> 6;
    if (tid == 0) nEmpty = 0;
    if (tid < T_N) {
        float4 tt = tboxes[b * T_N + tid];
        tb[tid] = tt;
        ta[tid] = (tt.z - tt.x) * (tt.w - tt.y);
    }

    unsigned long long K = 0ull;
    #pragma unroll 4
    for (int i = 0; i < 16; ++i) {
        unsigned long long k = keys[(((size_t)b * NB + (g * 16 + i)) << 6) | t];
        if (k > K) K = k;
    }
    sh[g][t] = K;
    __syncthreads();
    if (tid < 64) {
        unsigned long long m = sh[0][tid];
        #pragma unroll
        for (int g2 = 1; g2 < 16; ++g2) if (sh[g2][tid] > m) m = sh[g2][tid];
        unsigned int lo32 = (unsigned int)(m & 0xFFFFFFFFull);
        if (lo32 != 0u) winner[tid] = ~lo32;
        else { int i = atomicAdd(&nEmpty, 1); emptyList[i] = tid; }
    }
    __syncthreads();

    const int ne = nEmpty;            // normally 0
    for (int e = 0; e < ne; ++e) {
        const int tt = emptyList[e];
        const float4 tbx = tb[tt];
        const float tar = ta[tt];
        unsigned long long bk = 0ull;
        for (int i = tid; i < A_N; i += 1024) {
            float4 an = anchors[i];
            float a1 = (an.z - an.x) * (an.w - an.y);
            float iou = iou_fast(an, a1, tbx, tar);
            unsigned long long key = ((unsigned long long)__float_as_uint(iou) << 32)
                                   | (unsigned long long)(~(unsigned int)i);
            if (key > bk) bk = key;
        }
        #pragma unroll
        for (int off = 32; off; off >>= 1) {
            unsigned long long o = __shfl_down(bk, off, 64);
            if (o > bk) bk = o;
        }
        if ((tid & 63) == 0) sw[g] = bk;
        __syncthreads();
        if (tid == 0) {
            unsigned long long m = sw[0];
            #pragma unroll
            for (int i = 1; i < 16; ++i) if (sw[i] > m) m = sw[i];
            winner[tt] = ~(unsigned int)(m & 0xFFFFFFFFull);
        }
        __syncthreads();
    }

    // corrections: first wave, dedupe winners (lowest target owns), exact
    // row-argmax recompute for matched target.
    if (tid < 64) {
        const unsigned int wa = winner[tid];
        bool owner = true;
        for (int k = 0; k < 64; ++k) {
            unsigned int o = __shfl(wa, k, 64);
            if (k < tid && o == wa) owner = false;
        }
        const size_t ba = (size_t)b * A_N + wa;
        float d0 = 0.f, d1 = 0.f, d2 = 0.f, d3 = 0.f;
        if (owner && (code[ba] & 128) == 0) {
            const float4 aw = anchors[wa];
            const float aw1 = (aw.z - aw.x) * (aw.w - aw.y);
            unsigned int bb = 0u; int bt = 0;
            for (int s = 0; s < T_N; ++s) {
                float iou = iou_fast(aw, aw1, tb[s], ta[s]);
                unsigned int u = __float_as_uint(iou);
                if (u > bb) { bb = u; bt = s; }
            }
            const float p = conf[ba];
            d0 = conf_term(p, true) - conf_term(p, false);   // f0 cancels k1's term
            d1 = 1.f;
            d2 = bterm_at(bbox[ba], tb[bt]);
            d3 = cls_term(cls + ba * 5, (const float*)cls, ba,
                          tlabels[b * T_N + bt] - 1);
        }
        #pragma unroll
        for (int off = 32; off; off >>= 1) {
            d0 += __shfl_down(d0, off, 64);
            d1 += __shfl_down(d1, off, 64);
            d2 += __shfl_down(d2, off, 64);
            d3 += __shfl_down(d3, off, 64);
        }
        if (tid == 0) corr = make_float4(d0, d1, d2, d3);
    }
    __syncthreads();

    // finalize this image: sum 256 float4 partials + corr
    if (tid < NB) {
        float4 v = partials[(size_t)b * NB + tid];
        #pragma unroll
        for (int off = 32; off; off >>= 1) {
            v.x += __shfl_down(v.x, off, 64);
            v.y += __shfl_down(v.y, off, 64);
            v.z += __shfl_down(v.z, off, 64);
            v.w += __shfl_down(v.w, off, 64);
        }
        if ((tid & 63) == 0) redf[tid >> 6] = v;
    }
    __syncthreads();
    if (tid == 0) {
        float s0 = redf[0].x + redf[1].x + redf[2].x + redf[3].x + corr.x;
        float s1 = redf[0].y + redf[1].y + redf[2].y + redf[3].y + corr.y;
        float s2 = redf[0].z + redf[1].z + redf[2].z + redf[3].z + corr.z;
        float s3 = redf[0].w + redf[1].w + redf[2].w + redf[3].w + corr.w;
        float npos = fmaxf(s1, 1.f);
        // device-coherent writes (atomic path bypasses L1; cross-XCD safe)
        atomicExch(&lossImg[b * 3 + 0], s0 * (1.f / (float)A_N));
        atomicExch(&lossImg[b * 3 + 1], s2 / npos);
        atomicExch(&lossImg[b * 3 + 2], s3 / npos);
        __threadfence();
        unsigned int old = atomicAdd(done, 1u);
        lastFlag = (old == B_N - 1) ? 1 : 0;
    }
    __syncthreads();

    // last image-block averages all 16 images -> out[4]
    if (lastFlag && tid < 64) {
        __threadfence();
        float c = 0.f, bm = 0.f, l = 0.f;
        if (tid < B_N) {
            c  = atomicAdd(&lossImg[tid * 3 + 0], 0.f);   // coherent read
            bm = atomicAdd(&lossImg[tid * 3 + 1], 0.f);
            l  = atomicAdd(&lossImg[tid * 3 + 2], 0.f);
        }
        #pragma unroll
        for (int off = 8; off; off >>= 1) {
            c  += __shfl_down(c,  off, 64);
            bm += __shfl_down(bm, off, 64);
            l  += __shfl_down(l,  off, 64);
        }
        if (tid == 0) {
            c *= (1.f / 16.f); bm *= (1.f / 16.f); l *= (1.f / 16.f);
            out[0] = c + bm + l;
            out[1] = c;
            out[2] = bm;
            out[3] = l;
        }
    }
}

extern "C" void kernel_launch(void* const* d_in, const int* in_sizes, int n_in,
                              void* d_out, int out_size, void* d_ws, size_t ws_size,
                              hipStream_t stream)
{
    const float4* bbox    = (const float4*)d_in[0];
    const float*  conf    = (const float*) d_in[1];
    const float4* cls     = (const float4*)d_in[2];
    const float4* anchors = (const float4*)d_in[3];
    const float4* tboxes  = (const float4*)d_in[4];
    const int*    tlabels = (const int*)   d_in[5];
    float* out = (float*)d_out;

    char* ws = (char*)d_ws;
    unsigned long long* keys  = (unsigned long long*)ws;                   // 2 MiB
    unsigned char*      code  = (unsigned char*)(ws + (2u << 20));         // 1 MiB
    float4*       partials = (float4*)(ws + (3u << 20));                   // 64 KiB
    float*        lossImg  = (float*)(ws + (3u << 20) + (64u << 10));      // 192 B
    unsigned int* done     = (unsigned int*)(ws + (3u << 20) + (64u << 10) + 256);

    k1_main <<<dim3(NB, B_N), 256, 0, stream>>>(anchors, bbox, conf, cls, tboxes,
                                                tlabels, keys, code, partials, done);
    k2_all  <<<B_N, 1024, 0, stream>>>(keys, anchors, bbox, conf, cls, tboxes,
                                       tlabels, code, partials, lossImg, done, out);
}